// Round 1
// baseline (228.604 us; speedup 1.0000x reference)
//
#include <hip/hip_runtime.h>
#include <math.h>

// ---------------- persistent device scratch (bss, ~2.9 MB) ----------------
__device__ float g_G[64 * 16];                 // (X^T X)^-1 per SRN out-channel
__device__ float g_s1[64],  g_q1[64];          // bn1 stats accumulators
__device__ float g_s2[128], g_q2[128];
__device__ float g_s3[128], g_q3[128];
__device__ float g_s4[128], g_q4[128];
__device__ float g_h1[4 * 64 * 30 * 30];       // pooled SRN output
__device__ float g_h2[4 * 128 * 28 * 28];      // conv2 raw (pre-BN)
__device__ float g_h3[4 * 128 * 12 * 12];      // conv3 raw
__device__ float g_h4[4 * 128 * 4 * 4];        // conv4 raw

// ---------------- prep: zero stats + per-o 4x4 Gram inverse ----------------
__global__ void k_prep(const float* __restrict__ srn_w) {
    int t = threadIdx.x;  // 128 threads
    if (t < 64) { g_s1[t] = 0.f; g_q1[t] = 0.f; }
    if (t < 128) {
        g_s2[t] = 0.f; g_q2[t] = 0.f;
        g_s3[t] = 0.f; g_q3[t] = 0.f;
        g_s4[t] = 0.f; g_q4[t] = 0.f;
    }
    if (t < 64) {
        int o = t;
        const float* w = srn_w + o * 225;   // (75, 3) contiguous
        float c01 = 0, c02 = 0, c03 = 0, c11 = 0, c12 = 0, c13 = 0,
              c22 = 0, c23 = 0, c33 = 0;
        for (int n = 0; n < 75; n++) {
            float w1 = w[n * 3 + 0], w2 = w[n * 3 + 1], w3 = w[n * 3 + 2];
            c01 += w1; c02 += w2; c03 += w3;
            c11 += w1 * w1; c12 += w1 * w2; c13 += w1 * w3;
            c22 += w2 * w2; c23 += w2 * w3; c33 += w3 * w3;
        }
        float A[4][8];
        A[0][0] = 75.f; A[0][1] = c01; A[0][2] = c02; A[0][3] = c03;
        A[1][0] = c01;  A[1][1] = c11; A[1][2] = c12; A[1][3] = c13;
        A[2][0] = c02;  A[2][1] = c12; A[2][2] = c22; A[2][3] = c23;
        A[3][0] = c03;  A[3][1] = c13; A[3][2] = c23; A[3][3] = c33;
        for (int i = 0; i < 4; i++)
            for (int j = 0; j < 4; j++) A[i][4 + j] = (i == j) ? 1.f : 0.f;
        // Gauss-Jordan, no pivot (SPD Gram matrix, diag-dominant)
        for (int p = 0; p < 4; p++) {
            float ip = 1.f / A[p][p];
            for (int j = 0; j < 8; j++) A[p][j] *= ip;
            for (int i = 0; i < 4; i++) if (i != p) {
                float f = A[i][p];
                for (int j = 0; j < 8; j++) A[i][j] -= f * A[p][j];
            }
        }
        for (int i = 0; i < 4; i++)
            for (int j = 0; j < 4; j++) g_G[o * 16 + i * 4 + j] = A[i][4 + j];
    }
}

// ---------------- SRN + avgpool2 + bn1 stat accumulation ----------------
// grid 120 = (b, pooled row r); block 512 = 8 waves; lane = o, wave handles
// one of the two A-rows x a 15-wide ow strip.
__global__ __launch_bounds__(512, 2) void k_srn(const float* __restrict__ x,
                                                const float* __restrict__ srn_w) {
    __shared__ float xs[3 * 6 * 64];      // x rows 2r..2r+5, [c][rr][col]
    __shared__ float at[2 * 60 * 66];     // A tile [row][ow][ch(+pad)]
    int blk = blockIdx.x;
    int b = blk / 30, r = blk % 30;
    int t = threadIdx.x;

    for (int i = t; i < 3 * 6 * 64; i += 512) {
        int c = i / 384, rem = i % 384, rr = rem / 64, col = rem % 64;
        xs[i] = x[((b * 3 + c) * 64 + (2 * r + rr)) * 64 + col];
    }
    __syncthreads();

    int w = t >> 6, lane = t & 63;
    int row = w & 1, owb = (w >> 1) * 15;
    int o = lane;

    float g[16];
#pragma unroll
    for (int i = 0; i < 16; i++) g[i] = g_G[o * 16 + i];

    float z1[15], z2[15], z3[15], s[15], q[15];
#pragma unroll
    for (int i = 0; i < 15; i++) { z1[i] = 0; z2[i] = 0; z3[i] = 0; s[i] = 0; q[i] = 0; }

    const float* wo = srn_w + o * 225;
    for (int c = 0; c < 3; c++) {
#pragma unroll
        for (int kh = 0; kh < 5; kh++) {
            const float* xrow = &xs[(c * 6 + row + kh) * 64 + owb];
            float xv[19];
#pragma unroll
            for (int k = 0; k < 19; k++) xv[k] = xrow[k];
            const float* wn = wo + (c * 5 + kh) * 5 * 3;
#pragma unroll
            for (int kw = 0; kw < 5; kw++) {
                float w1 = wn[kw * 3 + 0], w2 = wn[kw * 3 + 1], w3 = wn[kw * 3 + 2];
#pragma unroll
                for (int i = 0; i < 15; i++) {
                    float v = xv[kw + i];
                    s[i] += v; q[i] += v * v;
                    z1[i] += w1 * v; z2[i] += w2 * v; z3[i] += w3 * v;
                }
            }
        }
    }

    const float C1 = 0.36787944117144233f;      // e^-1
    const float INV = 1.5819767068693265f;      // 1/(1-e^-1)
#pragma unroll
    for (int i = 0; i < 15; i++) {
        float sum = s[i], sq = q[i];
        float gg2 = (sq - sum * sum * (1.f / 75.f)) * (1.f / 74.f);   // unbiased var
        float zf[4] = { sum, z1[i], z2[i], z3[i] };
        float qf = 0.f;
#pragma unroll
        for (int f = 0; f < 4; f++) {
            float acc = 0.f;
#pragma unroll
            for (int h = 0; h < 4; h++) acc += g[f * 4 + h] * zf[h];
            qf += acc * zf[f];
        }
        float err = (sq - qf) / (75.f * gg2);
        float A = (expf(-err) - C1) * INV - 0.5f;
        at[(row * 60 + owb + i) * 66 + o] = A;
    }
    __syncthreads();

    // 2x2 avgpool -> g_h1, plus per-channel sum/sumsq
    int ch = t >> 3, j = t & 7;
    float ps = 0.f, pq = 0.f;
    for (int ow = j; ow < 30; ow += 8) {
        float v = 0.25f * (at[(2 * ow) * 66 + ch] + at[(2 * ow + 1) * 66 + ch]
                         + at[(60 + 2 * ow) * 66 + ch] + at[(60 + 2 * ow + 1) * 66 + ch]);
        g_h1[((b * 64 + ch) * 30 + r) * 30 + ow] = v;
        ps += v; pq += v * v;
    }
#pragma unroll
    for (int d = 1; d < 8; d <<= 1) { ps += __shfl_xor(ps, d); pq += __shfl_xor(pq, d); }
    if (j == 0) { atomicAdd(&g_s1[ch], ps); atomicAdd(&g_q1[ch], pq); }
}

// ---------------- bn1-apply + conv2 (no bias: BN cancels) + bn2 stats ------
// grid 112 = (b, oh); block 512 = oc(128) x ow-quarter(4)
__global__ __launch_bounds__(512) void k_conv2(const float* __restrict__ w2,
                                               const float* __restrict__ g1,
                                               const float* __restrict__ b1) {
    __shared__ float sc[64], sh[64];
    __shared__ float xs[64 * 3 * 30];
    __shared__ float redS[4][128], redQ[4][128];
    int blk = blockIdx.x; int b = blk / 28, oh = blk % 28;
    int t = threadIdx.x;
    if (t < 64) {
        float m = g_s1[t] * (1.f / 3600.f);
        float v = g_q1[t] * (1.f / 3600.f) - m * m;
        float rs = rsqrtf(v + 1e-5f);
        float scl = g1[t] * rs;
        sc[t] = scl; sh[t] = b1[t] - m * scl;
    }
    __syncthreads();
    for (int i = t; i < 64 * 3 * 30; i += 512) {
        int ic = i / 90, rem = i % 90, rr = rem / 30, col = rem % 30;
        xs[i] = g_h1[((b * 64 + ic) * 30 + oh + rr) * 30 + col] * sc[ic] + sh[ic];
    }
    __syncthreads();
    int oc = t & 127, qtr = t >> 7, owb = qtr * 7;
    float acc[7] = {0, 0, 0, 0, 0, 0, 0};
    const float* wp = w2 + oc * 576;
    for (int ic = 0; ic < 64; ic++) {
#pragma unroll
        for (int kh = 0; kh < 3; kh++) {
            const float* wq = wp + (ic * 3 + kh) * 3;
            float w0 = wq[0], w1 = wq[1], wv2 = wq[2];
            const float* xb = &xs[(ic * 3 + kh) * 30 + owb];
            float xv[9];
#pragma unroll
            for (int k = 0; k < 9; k++) xv[k] = xb[k];
#pragma unroll
            for (int i = 0; i < 7; i++)
                acc[i] += w0 * xv[i] + w1 * xv[i + 1] + wv2 * xv[i + 2];
        }
    }
    float ps = 0.f, pq = 0.f;
#pragma unroll
    for (int i = 0; i < 7; i++) {
        g_h2[((b * 128 + oc) * 28 + oh) * 28 + owb + i] = acc[i];
        ps += acc[i]; pq += acc[i] * acc[i];
    }
    redS[qtr][oc] = ps; redQ[qtr][oc] = pq;
    __syncthreads();
    if (t < 128) {
        atomicAdd(&g_s2[t], redS[0][t] + redS[1][t] + redS[2][t] + redS[3][t]);
        atomicAdd(&g_q2[t], redQ[0][t] + redQ[1][t] + redQ[2][t] + redQ[3][t]);
    }
}

// ------- bn2+relu+avgpool2 on the fly + conv3 + bn3 stats -------
// grid 48 = (b, oh in 12); block 512 = oc(128) x quarter(4), 3 ow each
__global__ __launch_bounds__(512) void k_conv3(const float* __restrict__ w3,
                                               const float* __restrict__ g2,
                                               const float* __restrict__ b2) {
    __shared__ float sc[128], sh[128];
    __shared__ float xs[128 * 3 * 14];
    __shared__ float redS[4][128], redQ[4][128];
    int blk = blockIdx.x; int b = blk / 12, oh = blk % 12;
    int t = threadIdx.x;
    if (t < 128) {
        float m = g_s2[t] * (1.f / 3136.f);
        float v = g_q2[t] * (1.f / 3136.f) - m * m;
        float rs = rsqrtf(v + 1e-5f);
        sc[t] = g2[t] * rs; sh[t] = b2[t] - m * sc[t];
    }
    __syncthreads();
    for (int i = t; i < 128 * 3 * 14; i += 512) {
        int ic = i / 42, rem = i % 42, rr = rem / 14, px = rem % 14;
        int p = oh + rr;
        const float* src = &g_h2[((b * 128 + ic) * 28 + 2 * p) * 28 + 2 * px];
        float s = sc[ic], h = sh[ic];
        float v00 = fmaxf(src[0] * s + h, 0.f), v01 = fmaxf(src[1] * s + h, 0.f);
        float v10 = fmaxf(src[28] * s + h, 0.f), v11 = fmaxf(src[29] * s + h, 0.f);
        xs[i] = 0.25f * (v00 + v01 + v10 + v11);
    }
    __syncthreads();
    int oc = t & 127, qtr = t >> 7, owb = qtr * 3;
    float acc[3] = {0, 0, 0};
    const float* wp = w3 + oc * 1152;
    for (int ic = 0; ic < 128; ic++) {
#pragma unroll
        for (int kh = 0; kh < 3; kh++) {
            const float* wq = wp + (ic * 3 + kh) * 3;
            float w0 = wq[0], w1 = wq[1], w2v = wq[2];
            const float* xb = &xs[(ic * 3 + kh) * 14 + owb];
            float x0 = xb[0], x1 = xb[1], x2 = xb[2], x3 = xb[3], x4 = xb[4];
            acc[0] += w0 * x0 + w1 * x1 + w2v * x2;
            acc[1] += w0 * x1 + w1 * x2 + w2v * x3;
            acc[2] += w0 * x2 + w1 * x3 + w2v * x4;
        }
    }
    float ps = 0.f, pq = 0.f;
#pragma unroll
    for (int i = 0; i < 3; i++) {
        g_h3[((b * 128 + oc) * 12 + oh) * 12 + owb + i] = acc[i];
        ps += acc[i]; pq += acc[i] * acc[i];
    }
    redS[qtr][oc] = ps; redQ[qtr][oc] = pq;
    __syncthreads();
    if (t < 128) {
        atomicAdd(&g_s3[t], redS[0][t] + redS[1][t] + redS[2][t] + redS[3][t]);
        atomicAdd(&g_q3[t], redQ[0][t] + redQ[1][t] + redQ[2][t] + redQ[3][t]);
    }
}

// ------- bn3+relu+maxpool2 on the fly + conv4 + bn4 stats -------
// grid 16 = (b, oh in 4); block 256 = oc(128) x half(2), 2 ow each
__global__ __launch_bounds__(256) void k_conv4(const float* __restrict__ w4,
                                               const float* __restrict__ g3,
                                               const float* __restrict__ b3) {
    __shared__ float sc[128], sh[128];
    __shared__ float xs[128 * 3 * 6];
    __shared__ float redS[2][128], redQ[2][128];
    int blk = blockIdx.x; int b = blk / 4, oh = blk % 4;
    int t = threadIdx.x;
    if (t < 128) {
        float m = g_s3[t] * (1.f / 576.f);
        float v = g_q3[t] * (1.f / 576.f) - m * m;
        float rs = rsqrtf(v + 1e-5f);
        sc[t] = g3[t] * rs; sh[t] = b3[t] - m * sc[t];
    }
    __syncthreads();
    for (int i = t; i < 128 * 3 * 6; i += 256) {
        int ic = i / 18, rem = i % 18, rr = rem / 6, px = rem % 6;
        int p = oh + rr;
        const float* src = &g_h3[((b * 128 + ic) * 12 + 2 * p) * 12 + 2 * px];
        float s = sc[ic], h = sh[ic];
        float v00 = fmaxf(src[0] * s + h, 0.f), v01 = fmaxf(src[1] * s + h, 0.f);
        float v10 = fmaxf(src[12] * s + h, 0.f), v11 = fmaxf(src[13] * s + h, 0.f);
        xs[i] = fmaxf(fmaxf(v00, v01), fmaxf(v10, v11));
    }
    __syncthreads();
    int oc = t & 127, half = t >> 7, owb = half * 2;
    float acc[2] = {0, 0};
    const float* wp = w4 + oc * 1152;
    for (int ic = 0; ic < 128; ic++) {
#pragma unroll
        for (int kh = 0; kh < 3; kh++) {
            const float* wq = wp + (ic * 3 + kh) * 3;
            float w0 = wq[0], w1 = wq[1], w2v = wq[2];
            const float* xb = &xs[(ic * 3 + kh) * 6 + owb];
            float x0 = xb[0], x1 = xb[1], x2 = xb[2], x3 = xb[3];
            acc[0] += w0 * x0 + w1 * x1 + w2v * x2;
            acc[1] += w0 * x1 + w1 * x2 + w2v * x3;
        }
    }
    g_h4[((b * 128 + oc) * 4 + oh) * 4 + owb]     = acc[0];
    g_h4[((b * 128 + oc) * 4 + oh) * 4 + owb + 1] = acc[1];
    redS[half][oc] = acc[0] + acc[1];
    redQ[half][oc] = acc[0] * acc[0] + acc[1] * acc[1];
    __syncthreads();
    if (t < 128) {
        atomicAdd(&g_s4[t], redS[0][t] + redS[1][t]);
        atomicAdd(&g_q4[t], redQ[0][t] + redQ[1][t]);
    }
}

// ------- bn4+relu+maxpool4 + FC -------
__global__ __launch_bounds__(256) void k_final(const float* __restrict__ g4,
                                               const float* __restrict__ b4,
                                               const float* __restrict__ fcw,
                                               const float* __restrict__ fcb,
                                               float* __restrict__ out) {
    __shared__ float sc[128], sh[128];
    __shared__ float pooled[4][128];
    int t = threadIdx.x;
    if (t < 128) {
        float m = g_s4[t] * (1.f / 64.f);
        float v = g_q4[t] * (1.f / 64.f) - m * m;
        float rs = rsqrtf(v + 1e-5f);
        sc[t] = g4[t] * rs; sh[t] = b4[t] - m * sc[t];
    }
    __syncthreads();
    for (int item = t; item < 512; item += 256) {
        int b = item >> 7, oc = item & 127;
        const float* src = &g_h4[(b * 128 + oc) * 16];
        float s = sc[oc], h = sh[oc];
        float mx = 0.f;   // relu then max == max(0, max)
#pragma unroll
        for (int k = 0; k < 16; k++) mx = fmaxf(mx, src[k] * s + h);
        pooled[b][oc] = mx;
    }
    __syncthreads();
    if (t < 20) {
        int b = t / 5, cls = t % 5;
        float acc = fcb[cls];
        const float* w = &fcw[cls * 128];
        for (int oc = 0; oc < 128; oc++) acc += pooled[b][oc] * w[oc];
        out[b * 5 + cls] = acc;
    }
}

extern "C" void kernel_launch(void* const* d_in, const int* in_sizes, int n_in,
                              void* d_out, int out_size, void* d_ws, size_t ws_size,
                              hipStream_t stream) {
    (void)in_sizes; (void)n_in; (void)out_size; (void)d_ws; (void)ws_size;
    const float* x     = (const float*)d_in[0];
    const float* srn_w = (const float*)d_in[1];
    const float* w2    = (const float*)d_in[2];
    const float* w3    = (const float*)d_in[4];
    const float* w4    = (const float*)d_in[6];
    const float* g1 = (const float*)d_in[8];  const float* b1 = (const float*)d_in[9];
    const float* g2 = (const float*)d_in[10]; const float* b2 = (const float*)d_in[11];
    const float* g3 = (const float*)d_in[12]; const float* b3 = (const float*)d_in[13];
    const float* g4 = (const float*)d_in[14]; const float* b4 = (const float*)d_in[15];
    const float* fcw = (const float*)d_in[16]; const float* fcb = (const float*)d_in[17];
    float* out = (float*)d_out;

    k_prep <<<dim3(1),   dim3(128), 0, stream>>>(srn_w);
    k_srn  <<<dim3(120), dim3(512), 0, stream>>>(x, srn_w);
    k_conv2<<<dim3(112), dim3(512), 0, stream>>>(w2, g1, b1);
    k_conv3<<<dim3(48),  dim3(512), 0, stream>>>(w3, g2, b2);
    k_conv4<<<dim3(16),  dim3(256), 0, stream>>>(w4, g3, b3);
    k_final<<<dim3(1),   dim3(256), 0, stream>>>(g4, b4, fcw, fcb, out);
}

// Round 2
// 211.913 us; speedup vs baseline: 1.0788x; 1.0788x over previous
//
#include <hip/hip_runtime.h>
#include <math.h>

// ---------------- persistent device scratch ----------------
__device__ __align__(16) float g_G[64 * 16];    // (X^T X)^-1 per SRN out-channel
__device__ __align__(16) float g_Wp[64 * 240];  // repacked srn weights [o][15 rows][16]
__device__ float g_s1[64],  g_q1[64];
__device__ float g_s2[128], g_q2[128];
__device__ float g_s3[128], g_q3[128];
__device__ float g_s4[128], g_q4[128];
__device__ float g_h1[4 * 30 * 30 * 64];        // pooled SRN out, channel-LAST
__device__ float g_h2[4 * 28 * 28 * 128];       // conv2 raw, channel-LAST
__device__ float g_h3[4 * 12 * 12 * 128];       // conv3 raw, channel-LAST
__device__ float g_h4[4 * 4 * 4 * 128];         // conv4 raw, channel-LAST

// ------------- prep: zero stats + Gram inverse + weight repack -------------
__global__ void k_prep(const float* __restrict__ srn_w) {
    int t = threadIdx.x, bid = blockIdx.x;
    // repack srn weights: [o][(c*5+kh)*15 + kw*3+s] -> [o*240 + row*16 + col]
    for (int i = bid * 256 + t; i < 14400; i += 8 * 256) {
        int o = i / 225, j = i % 225, row = j / 15, col = j % 15;
        g_Wp[o * 240 + row * 16 + col] = srn_w[i];
    }
    if (bid == 0) {
        if (t < 64) { g_s1[t] = 0.f; g_q1[t] = 0.f; }
        if (t < 128) {
            g_s2[t] = 0.f; g_q2[t] = 0.f;
            g_s3[t] = 0.f; g_q3[t] = 0.f;
            g_s4[t] = 0.f; g_q4[t] = 0.f;
        }
        if (t < 64) {
            int o = t;
            const float* w = srn_w + o * 225;
            float c01 = 0, c02 = 0, c03 = 0, c11 = 0, c12 = 0, c13 = 0,
                  c22 = 0, c23 = 0, c33 = 0;
            for (int n = 0; n < 75; n++) {
                float w1 = w[n * 3 + 0], w2 = w[n * 3 + 1], w3 = w[n * 3 + 2];
                c01 += w1; c02 += w2; c03 += w3;
                c11 += w1 * w1; c12 += w1 * w2; c13 += w1 * w3;
                c22 += w2 * w2; c23 += w2 * w3; c33 += w3 * w3;
            }
            float A[4][8];
            A[0][0] = 75.f; A[0][1] = c01; A[0][2] = c02; A[0][3] = c03;
            A[1][0] = c01;  A[1][1] = c11; A[1][2] = c12; A[1][3] = c13;
            A[2][0] = c02;  A[2][1] = c12; A[2][2] = c22; A[2][3] = c23;
            A[3][0] = c03;  A[3][1] = c13; A[3][2] = c23; A[3][3] = c33;
            for (int i = 0; i < 4; i++)
                for (int j = 0; j < 4; j++) A[i][4 + j] = (i == j) ? 1.f : 0.f;
            for (int p = 0; p < 4; p++) {
                float ip = 1.f / A[p][p];
                for (int j = 0; j < 8; j++) A[p][j] *= ip;
                for (int i = 0; i < 4; i++) if (i != p) {
                    float f = A[i][p];
                    for (int j = 0; j < 8; j++) A[i][j] -= f * A[p][j];
                }
            }
            for (int i = 0; i < 4; i++)
                for (int j = 0; j < 4; j++) g_G[o * 16 + i * 4 + j] = A[i][4 + j];
        }
    }
}

// ---------------- SRN + avgpool2 + bn1 stats ----------------
// grid 240 = (b, pooled row r, col-half); block 256 = 4 waves:
// wave = (pre-pool row rw in {0,1}, col-quarter cq in {0,1}); lane = o.
// Each lane: 16 pre-pool positions, weights streamed as aligned float4 from g_Wp.
__global__ __launch_bounds__(256, 2) void k_srn(const float* __restrict__ x) {
    __shared__ float xs[3 * 6 * 36];          // rows 2r..2r+5, 36 cols (clamped)
    __shared__ float part[2 * 15 * 66];       // per-row pooled partials [rw][pl][o]
    __shared__ float redS[256], redQ[256];
    int blk = blockIdx.x;
    int b = blk / 60, rem = blk % 60, r = rem >> 1, ch = rem & 1;
    int t = threadIdx.x;

    for (int i = t; i < 648; i += 256) {
        int c = i / 216, rm = i % 216, rr = rm / 36, col = rm % 36;
        int gc = ch * 30 + col; if (gc > 63) gc = 63;   // clamp (masked lanes only)
        xs[i] = x[((b * 3 + c) * 64 + (2 * r + rr)) * 64 + gc];
    }
    __syncthreads();

    int w = t >> 6, o = t & 63;
    int rw = w & 1, cq = w >> 1, base = cq * 16;

    float z1[16], z2[16], z3[16], s[16], q[16];
#pragma unroll
    for (int i = 0; i < 16; i++) { z1[i] = 0; z2[i] = 0; z3[i] = 0; s[i] = 0; q[i] = 0; }

    for (int c = 0; c < 3; c++) {
#pragma unroll
        for (int kh = 0; kh < 5; kh++) {
            float xv[20];
#pragma unroll
            for (int k = 0; k < 20; k++) xv[k] = xs[(c * 6 + rw + kh) * 36 + base + k];
            float wf[16];
            const float4* wp = (const float4*)&g_Wp[o * 240 + (c * 5 + kh) * 16];
            *(float4*)&wf[0]  = wp[0]; *(float4*)&wf[4]  = wp[1];
            *(float4*)&wf[8]  = wp[2]; *(float4*)&wf[12] = wp[3];
#pragma unroll
            for (int kw = 0; kw < 5; kw++) {
                float w1 = wf[kw * 3], w2 = wf[kw * 3 + 1], w3 = wf[kw * 3 + 2];
#pragma unroll
                for (int i = 0; i < 16; i++) {
                    float v = xv[kw + i];
                    s[i] += v; q[i] += v * v;
                    z1[i] += w1 * v; z2[i] += w2 * v; z3[i] += w3 * v;
                }
            }
        }
    }

    float gm[16];
    {
        const float4* gp = (const float4*)&g_G[o * 16];
        *(float4*)&gm[0]  = gp[0]; *(float4*)&gm[4]  = gp[1];
        *(float4*)&gm[8]  = gp[2]; *(float4*)&gm[12] = gp[3];
    }
    const float C1 = 0.36787944117144233f;
    const float INV = 1.5819767068693265f;
#pragma unroll
    for (int pp = 0; pp < 8; pp++) {
        int pl = cq * 8 + pp;
        if (pl < 15) {
            float aa = 0.f;
#pragma unroll
            for (int e = 0; e < 2; e++) {
                int i = 2 * pp + e;
                float sum = s[i], sq = q[i];
                float gg2 = (sq - sum * sum * (1.f / 75.f)) * (1.f / 74.f);
                float zf[4] = { sum, z1[i], z2[i], z3[i] };
                float qf = 0.f;
#pragma unroll
                for (int f = 0; f < 4; f++) {
                    float acc = 0.f;
#pragma unroll
                    for (int h = 0; h < 4; h++) acc += gm[f * 4 + h] * zf[h];
                    qf += acc * zf[f];
                }
                float err = (sq - qf) / (75.f * gg2);
                aa += (expf(-err) - C1) * INV - 0.5f;
            }
            part[(rw * 15 + pl) * 66 + o] = 0.25f * aa;
        }
    }
    __syncthreads();

    int j = t >> 6;
    float ps = 0.f, pq = 0.f;
    for (int pl = j; pl < 15; pl += 4) {
        float v = part[pl * 66 + o] + part[(15 + pl) * 66 + o];
        g_h1[((b * 30 + r) * 30 + ch * 15 + pl) * 64 + o] = v;
        ps += v; pq += v * v;
    }
    redS[t] = ps; redQ[t] = pq;
    __syncthreads();
    if (t < 64) {
        atomicAdd(&g_s1[t], redS[t] + redS[64 + t] + redS[128 + t] + redS[192 + t]);
        atomicAdd(&g_q1[t], redQ[t] + redQ[64 + t] + redQ[128 + t] + redQ[192 + t]);
    }
}

// -------- bn1-apply + conv2 + bn2 stats --------
// grid 224 = (b, oh, ocg); block 256 = oc_l(64) x qtr(4, 7 ow each).
// Weights LDS [oc][48 rows][4] stride 196 (==4 mod 32: perfect b128 banking).
__global__ __launch_bounds__(256) void k_conv2(const float* __restrict__ w2,
                                               const float* __restrict__ g1,
                                               const float* __restrict__ b1) {
    __shared__ float sc[64], sh[64];
    __shared__ __align__(16) float ws[64 * 196];
    __shared__ float xs[16 * 3 * 30];
    __shared__ float redS[256], redQ[256];
    int blk = blockIdx.x;
    int b = blk / 56, rem = blk % 56, oh = rem >> 1, ocg = rem & 1;
    int t = threadIdx.x;
    if (t < 64) {
        float m = g_s1[t] * (1.f / 3600.f);
        float v = g_q1[t] * (1.f / 3600.f) - m * m;
        float rs = rsqrtf(v + 1e-5f);
        sc[t] = g1[t] * rs; sh[t] = b1[t] - m * sc[t];
    }
    __syncthreads();
    int oc_l = t & 63, qtr = t >> 6, owb = qtr * 7;
    float acc[7] = {0, 0, 0, 0, 0, 0, 0};
    for (int it = 0; it < 4; it++) {
        int icb = it * 16;
        for (int i = t; i < 64 * 144; i += 256) {
            int oc = i / 144, j = i % 144, ic = j / 9, rr = j % 9;
            ws[oc * 196 + (ic * 3 + rr / 3) * 4 + rr % 3] =
                w2[(ocg * 64 + oc) * 576 + (icb + ic) * 9 + rr];
        }
        for (int i = t; i < 1440; i += 256) {
            int ic = i & 15, qq = i >> 4, col = qq % 30, rr = qq / 30;
            xs[(ic * 3 + rr) * 30 + col] =
                g_h1[((b * 30 + oh + rr) * 30 + col) * 64 + icb + ic] * sc[icb + ic] + sh[icb + ic];
        }
        __syncthreads();
        for (int ic = 0; ic < 16; ic++) {
#pragma unroll
            for (int kh = 0; kh < 3; kh++) {
                float4 wv = *(const float4*)&ws[oc_l * 196 + (ic * 3 + kh) * 4];
                float xv[9];
#pragma unroll
                for (int k = 0; k < 9; k++) xv[k] = xs[(ic * 3 + kh) * 30 + owb + k];
#pragma unroll
                for (int i = 0; i < 7; i++)
                    acc[i] += wv.x * xv[i] + wv.y * xv[i + 1] + wv.z * xv[i + 2];
            }
        }
        __syncthreads();
    }
    int oc = ocg * 64 + oc_l;
    float ps = 0.f, pq = 0.f;
#pragma unroll
    for (int i = 0; i < 7; i++) {
        g_h2[((b * 28 + oh) * 28 + owb + i) * 128 + oc] = acc[i];
        ps += acc[i]; pq += acc[i] * acc[i];
    }
    redS[t] = ps; redQ[t] = pq;
    __syncthreads();
    if (t < 64) {
        atomicAdd(&g_s2[ocg * 64 + t], redS[t] + redS[64 + t] + redS[128 + t] + redS[192 + t]);
        atomicAdd(&g_q2[ocg * 64 + t], redQ[t] + redQ[64 + t] + redQ[128 + t] + redQ[192 + t]);
    }
}

// -------- bn2+relu+avgpool2 + conv3 + bn3 stats --------
// grid 96 = (b, oh in 12, ocg); block 256 = oc_l(64) x qtr(4, 3 ow each).
__global__ __launch_bounds__(256) void k_conv3(const float* __restrict__ w3,
                                               const float* __restrict__ g2,
                                               const float* __restrict__ b2) {
    __shared__ float sc[128], sh[128];
    __shared__ __align__(16) float ws[64 * 196];
    __shared__ float xs[16 * 3 * 14];
    __shared__ float redS[256], redQ[256];
    int blk = blockIdx.x;
    int b = blk / 24, rem = blk % 24, oh = rem >> 1, ocg = rem & 1;
    int t = threadIdx.x;
    if (t < 128) {
        float m = g_s2[t] * (1.f / 3136.f);
        float v = g_q2[t] * (1.f / 3136.f) - m * m;
        float rs = rsqrtf(v + 1e-5f);
        sc[t] = g2[t] * rs; sh[t] = b2[t] - m * sc[t];
    }
    __syncthreads();
    int oc_l = t & 63, qtr = t >> 6, owb = qtr * 3;
    float acc[3] = {0, 0, 0};
    for (int it = 0; it < 8; it++) {
        int icb = it * 16;
        for (int i = t; i < 64 * 144; i += 256) {
            int oc = i / 144, j = i % 144, ic = j / 9, rr = j % 9;
            ws[oc * 196 + (ic * 3 + rr / 3) * 4 + rr % 3] =
                w3[(ocg * 64 + oc) * 1152 + (icb + ic) * 9 + rr];
        }
        for (int i = t; i < 672; i += 256) {
            int ic = i & 15, qq = i >> 4, px = qq % 14, rr = qq / 14;
            int R = 2 * (oh + rr), C = 2 * px;
            const float* p0 = &g_h2[((b * 28 + R) * 28 + C) * 128 + icb + ic];
            float scv = sc[icb + ic], shv = sh[icb + ic];
            float v00 = fmaxf(p0[0] * scv + shv, 0.f);
            float v01 = fmaxf(p0[128] * scv + shv, 0.f);
            float v10 = fmaxf(p0[28 * 128] * scv + shv, 0.f);
            float v11 = fmaxf(p0[29 * 128] * scv + shv, 0.f);
            xs[(ic * 3 + rr) * 14 + px] = 0.25f * (v00 + v01 + v10 + v11);
        }
        __syncthreads();
        for (int ic = 0; ic < 16; ic++) {
#pragma unroll
            for (int kh = 0; kh < 3; kh++) {
                float4 wv = *(const float4*)&ws[oc_l * 196 + (ic * 3 + kh) * 4];
                float xv[5];
#pragma unroll
                for (int k = 0; k < 5; k++) xv[k] = xs[(ic * 3 + kh) * 14 + owb + k];
#pragma unroll
                for (int i = 0; i < 3; i++)
                    acc[i] += wv.x * xv[i] + wv.y * xv[i + 1] + wv.z * xv[i + 2];
            }
        }
        __syncthreads();
    }
    int oc = ocg * 64 + oc_l;
    float ps = 0.f, pq = 0.f;
#pragma unroll
    for (int i = 0; i < 3; i++) {
        g_h3[((b * 12 + oh) * 12 + owb + i) * 128 + oc] = acc[i];
        ps += acc[i]; pq += acc[i] * acc[i];
    }
    redS[t] = ps; redQ[t] = pq;
    __syncthreads();
    if (t < 64) {
        atomicAdd(&g_s3[ocg * 64 + t], redS[t] + redS[64 + t] + redS[128 + t] + redS[192 + t]);
        atomicAdd(&g_q3[ocg * 64 + t], redQ[t] + redQ[64 + t] + redQ[128 + t] + redQ[192 + t]);
    }
}

// -------- bn3+relu+maxpool2 + conv4 + bn4 stats --------
// grid 32 = (b, oh in 4, ocg); block 256 = oc_l(64) x ow(4).
__global__ __launch_bounds__(256) void k_conv4(const float* __restrict__ w4,
                                               const float* __restrict__ g3,
                                               const float* __restrict__ b3) {
    __shared__ float sc[128], sh[128];
    __shared__ __align__(16) float ws[64 * 196];
    __shared__ float xs[16 * 3 * 6];
    __shared__ float redS[256], redQ[256];
    int blk = blockIdx.x;
    int b = blk / 8, rem = blk % 8, oh = rem >> 1, ocg = rem & 1;
    int t = threadIdx.x;
    if (t < 128) {
        float m = g_s3[t] * (1.f / 576.f);
        float v = g_q3[t] * (1.f / 576.f) - m * m;
        float rs = rsqrtf(v + 1e-5f);
        sc[t] = g3[t] * rs; sh[t] = b3[t] - m * sc[t];
    }
    __syncthreads();
    int oc_l = t & 63, ow = t >> 6;
    float acc = 0.f;
    for (int it = 0; it < 8; it++) {
        int icb = it * 16;
        for (int i = t; i < 64 * 144; i += 256) {
            int oc = i / 144, j = i % 144, ic = j / 9, rr = j % 9;
            ws[oc * 196 + (ic * 3 + rr / 3) * 4 + rr % 3] =
                w4[(ocg * 64 + oc) * 1152 + (icb + ic) * 9 + rr];
        }
        for (int i = t; i < 288; i += 256) {
            int ic = i & 15, qq = i >> 4, px = qq % 6, rr = qq / 6;
            int R = 2 * (oh + rr), C = 2 * px;
            const float* p0 = &g_h3[((b * 12 + R) * 12 + C) * 128 + icb + ic];
            float scv = sc[icb + ic], shv = sh[icb + ic];
            float v00 = fmaxf(p0[0] * scv + shv, 0.f);
            float v01 = fmaxf(p0[128] * scv + shv, 0.f);
            float v10 = fmaxf(p0[12 * 128] * scv + shv, 0.f);
            float v11 = fmaxf(p0[13 * 128] * scv + shv, 0.f);
            xs[(ic * 3 + rr) * 6 + px] = fmaxf(fmaxf(v00, v01), fmaxf(v10, v11));
        }
        __syncthreads();
        for (int ic = 0; ic < 16; ic++) {
#pragma unroll
            for (int kh = 0; kh < 3; kh++) {
                float4 wv = *(const float4*)&ws[oc_l * 196 + (ic * 3 + kh) * 4];
                const float* xb = &xs[(ic * 3 + kh) * 6 + ow];
                acc += wv.x * xb[0] + wv.y * xb[1] + wv.z * xb[2];
            }
        }
        __syncthreads();
    }
    int oc = ocg * 64 + oc_l;
    g_h4[((b * 4 + oh) * 4 + ow) * 128 + oc] = acc;
    redS[t] = acc; redQ[t] = acc * acc;
    __syncthreads();
    if (t < 64) {
        atomicAdd(&g_s4[ocg * 64 + t], redS[t] + redS[64 + t] + redS[128 + t] + redS[192 + t]);
        atomicAdd(&g_q4[ocg * 64 + t], redQ[t] + redQ[64 + t] + redQ[128 + t] + redQ[192 + t]);
    }
}

// ------- bn4+relu+maxpool4 + FC -------
__global__ __launch_bounds__(256) void k_final(const float* __restrict__ g4,
                                               const float* __restrict__ b4,
                                               const float* __restrict__ fcw,
                                               const float* __restrict__ fcb,
                                               float* __restrict__ out) {
    __shared__ float sc[128], sh[128];
    __shared__ float pooled[4][128];
    int t = threadIdx.x;
    if (t < 128) {
        float m = g_s4[t] * (1.f / 64.f);
        float v = g_q4[t] * (1.f / 64.f) - m * m;
        float rs = rsqrtf(v + 1e-5f);
        sc[t] = g4[t] * rs; sh[t] = b4[t] - m * sc[t];
    }
    __syncthreads();
    for (int item = t; item < 512; item += 256) {
        int b = item >> 7, oc = item & 127;
        float s = sc[oc], h = sh[oc];
        float mx = 0.f;
#pragma unroll
        for (int k = 0; k < 16; k++) mx = fmaxf(mx, g_h4[(b * 16 + k) * 128 + oc] * s + h);
        pooled[b][oc] = mx;
    }
    __syncthreads();
    if (t < 20) {
        int b = t / 5, cls = t % 5;
        float acc = fcb[cls];
        const float* w = &fcw[cls * 128];
        for (int oc = 0; oc < 128; oc++) acc += pooled[b][oc] * w[oc];
        out[b * 5 + cls] = acc;
    }
}

extern "C" void kernel_launch(void* const* d_in, const int* in_sizes, int n_in,
                              void* d_out, int out_size, void* d_ws, size_t ws_size,
                              hipStream_t stream) {
    (void)in_sizes; (void)n_in; (void)out_size; (void)d_ws; (void)ws_size;
    const float* x     = (const float*)d_in[0];
    const float* srn_w = (const float*)d_in[1];
    const float* w2    = (const float*)d_in[2];
    const float* w3    = (const float*)d_in[4];
    const float* w4    = (const float*)d_in[6];
    const float* g1 = (const float*)d_in[8];  const float* b1 = (const float*)d_in[9];
    const float* g2 = (const float*)d_in[10]; const float* b2 = (const float*)d_in[11];
    const float* g3 = (const float*)d_in[12]; const float* b3 = (const float*)d_in[13];
    const float* g4 = (const float*)d_in[14]; const float* b4 = (const float*)d_in[15];
    const float* fcw = (const float*)d_in[16]; const float* fcb = (const float*)d_in[17];
    float* out = (float*)d_out;

    k_prep <<<dim3(8),   dim3(256), 0, stream>>>(srn_w);
    k_srn  <<<dim3(240), dim3(256), 0, stream>>>(x);
    k_conv2<<<dim3(224), dim3(256), 0, stream>>>(w2, g1, b1);
    k_conv3<<<dim3(96),  dim3(256), 0, stream>>>(w3, g2, b2);
    k_conv4<<<dim3(32),  dim3(256), 0, stream>>>(w4, g3, b3);
    k_final<<<dim3(1),   dim3(256), 0, stream>>>(g4, b4, fcw, fcb, out);
}

// Round 3
// 168.242 us; speedup vs baseline: 1.3588x; 1.2596x over previous
//
#include <hip/hip_runtime.h>
#include <math.h>

// ---------------- persistent device scratch ----------------
__device__ __align__(16) float g_G[64 * 16];     // (X^T X)^-1 per SRN channel
__device__ __align__(16) float g_Wp[64 * 240];   // srn weights [o][15 rows][16]
__device__ __align__(16) float g_w2p[9 * 2304 * 4];   // conv2 staging-order (+1 pad tile)
__device__ __align__(16) float g_w3p[17 * 2304 * 4];  // conv3 staging-order (+1 pad tile)
__device__ __align__(16) float g_w4p[8 * 4608 * 4];   // conv4 staging-order
__device__ float g_s1[64],  g_q1[64];
__device__ float g_s2[128], g_q2[128];
__device__ float g_s3[128], g_q3[128];
__device__ float g_s4[128], g_q4[128];
__device__ __align__(16) float g_h1[4 * 30 * 30 * 64];   // [b][r][c][ic]
__device__ __align__(16) float g_h2[4 * 14 * 14 * 4 * 128]; // pool-pair layout
__device__ __align__(16) float g_h3[4 * 6 * 6 * 4 * 128];   // pool-pair layout
__device__ __align__(16) float g_h4[4 * 16 * 128];

// ------------- prep: zero stats + Gram inverse + weight repacks -------------
__global__ void k_prep(const float* __restrict__ srn_w, const float* __restrict__ w2,
                       const float* __restrict__ w3, const float* __restrict__ w4) {
    int t = threadIdx.x, bid = blockIdx.x;
    int gid = bid * 256 + t, gstride = 128 * 256;
    for (int i = gid; i < 14400; i += gstride) {
        int o = i / 225, j = i % 225, row = j / 15, col = j % 15;
        g_Wp[o * 240 + row * 16 + col] = srn_w[i];
    }
    // conv2: [blk=ocg*4+it][oc_l][sl=(kh*4+icq)*3+kw][c=ic%4]
    for (int j = gid; j < 73728; j += gstride) {
        int c = j & 3, s4 = j >> 2;
        int sl = s4 % 36, tmp = s4 / 36, oc_l = tmp & 63, blk = tmp >> 6;
        int it = blk & 3, ocg = blk >> 2;
        int kw = sl % 3, icq = (sl / 3) & 3, kh = sl / 12;
        int ic = it * 16 + icq * 4 + c;
        g_w2p[j] = w2[((ocg * 64 + oc_l) * 64 + ic) * 9 + kh * 3 + kw];
    }
    // conv3: [blk=ocg*8+it][oc_l][sl][c]
    for (int j = gid; j < 147456; j += gstride) {
        int c = j & 3, s4 = j >> 2;
        int sl = s4 % 36, tmp = s4 / 36, oc_l = tmp & 63, blk = tmp >> 6;
        int it = blk & 7, ocg = blk >> 3;
        int kw = sl % 3, icq = (sl / 3) & 3, kh = sl / 12;
        int ic = it * 16 + icq * 4 + c;
        g_w3p[j] = w3[((ocg * 64 + oc_l) * 128 + ic) * 9 + kh * 3 + kw];
    }
    // conv4: [ocg][icq][oc_l][sl=(kh*8+icb)*3+kw][c]
    for (int j = gid; j < 147456; j += gstride) {
        int c = j & 3, s4 = j >> 2;
        int sl = s4 % 72, tmp = s4 / 72, oc_l = tmp & 15, blkq = tmp >> 4;
        int icq = blkq & 3, ocg = blkq >> 2;
        int kw = sl % 3, icb = (sl / 3) & 7, kh = sl / 24;
        int ic = icq * 32 + icb * 4 + c;
        g_w4p[j] = w4[((ocg * 16 + oc_l) * 128 + ic) * 9 + kh * 3 + kw];
    }
    if (bid == 0) {
        if (t < 64) { g_s1[t] = 0.f; g_q1[t] = 0.f; }
        if (t < 128) {
            g_s2[t] = 0.f; g_q2[t] = 0.f;
            g_s3[t] = 0.f; g_q3[t] = 0.f;
            g_s4[t] = 0.f; g_q4[t] = 0.f;
        }
        if (t < 64) {
            int o = t;
            const float* w = srn_w + o * 225;
            float c01 = 0, c02 = 0, c03 = 0, c11 = 0, c12 = 0, c13 = 0,
                  c22 = 0, c23 = 0, c33 = 0;
            for (int n = 0; n < 75; n++) {
                float w1 = w[n * 3 + 0], w2v = w[n * 3 + 1], w3v = w[n * 3 + 2];
                c01 += w1; c02 += w2v; c03 += w3v;
                c11 += w1 * w1; c12 += w1 * w2v; c13 += w1 * w3v;
                c22 += w2v * w2v; c23 += w2v * w3v; c33 += w3v * w3v;
            }
            float A[4][8];
            A[0][0] = 75.f; A[0][1] = c01; A[0][2] = c02; A[0][3] = c03;
            A[1][0] = c01;  A[1][1] = c11; A[1][2] = c12; A[1][3] = c13;
            A[2][0] = c02;  A[2][1] = c12; A[2][2] = c22; A[2][3] = c23;
            A[3][0] = c03;  A[3][1] = c13; A[3][2] = c23; A[3][3] = c33;
            for (int i = 0; i < 4; i++)
                for (int j = 0; j < 4; j++) A[i][4 + j] = (i == j) ? 1.f : 0.f;
            for (int p = 0; p < 4; p++) {
                float ip = 1.f / A[p][p];
                for (int j = 0; j < 8; j++) A[p][j] *= ip;
                for (int i = 0; i < 4; i++) if (i != p) {
                    float f = A[i][p];
                    for (int j = 0; j < 8; j++) A[i][j] -= f * A[p][j];
                }
            }
            for (int i = 0; i < 4; i++)
                for (int j = 0; j < 4; j++) g_G[o * 16 + i * 4 + j] = A[i][4 + j];
        }
    }
}

// ---------------- SRN + avgpool2 + bn1 stats ----------------
__global__ __launch_bounds__(256) void k_srn(const float* __restrict__ x) {
    __shared__ __align__(16) float wlds[64 * 244];
    __shared__ __align__(16) float glds[64 * 20];
    __shared__ float xsm[648];
    __shared__ float part[2 * 15 * 66];
    __shared__ float redS[256], redQ[256];
    int blk = blockIdx.x;
    int b = blk / 60, rem = blk % 60, r = rem >> 1, ch = rem & 1;
    int t = threadIdx.x;

    // batched prefetch: weights (15 f4), G (1 f4), x (3 scalars)
    float4 wreg[15];
#pragma unroll
    for (int k = 0; k < 15; k++) wreg[k] = ((const float4*)g_Wp)[k * 256 + t];
    float4 greg = ((const float4*)g_G)[t];
    float xr[3];
#pragma unroll
    for (int k = 0; k < 3; k++) {
        int i = t + k * 256;
        if (i < 648) {
            int c = i / 216, rm = i % 216, rr = rm / 36, col = rm % 36;
            int gc = ch * 30 + col; if (gc > 63) gc = 63;
            xr[k] = x[((b * 3 + c) * 64 + (2 * r + rr)) * 64 + gc];
        }
    }
#pragma unroll
    for (int k = 0; k < 15; k++) {
        int idx = k * 256 + t;
        *(float4*)&wlds[(idx / 60) * 244 + (idx % 60) * 4] = wreg[k];
    }
    *(float4*)&glds[(t >> 2) * 20 + (t & 3) * 4] = greg;
#pragma unroll
    for (int k = 0; k < 3; k++) { int i = t + k * 256; if (i < 648) xsm[i] = xr[k]; }
    __syncthreads();

    int w = t >> 6, o = t & 63;
    int rw = w & 1, cq = w >> 1, base = cq * 16;

    float z1[16], z2[16], z3[16], s[16], q[16];
#pragma unroll
    for (int i = 0; i < 16; i++) { z1[i] = 0; z2[i] = 0; z3[i] = 0; s[i] = 0; q[i] = 0; }

    for (int c = 0; c < 3; c++) {
#pragma unroll
        for (int kh = 0; kh < 5; kh++) {
            float xv[20];
#pragma unroll
            for (int k = 0; k < 20; k++) xv[k] = xsm[(c * 6 + rw + kh) * 36 + base + k];
            float wf[16];
            const float* wp = &wlds[o * 244 + (c * 5 + kh) * 16];
            *(float4*)&wf[0]  = *(const float4*)&wp[0];
            *(float4*)&wf[4]  = *(const float4*)&wp[4];
            *(float4*)&wf[8]  = *(const float4*)&wp[8];
            *(float4*)&wf[12] = *(const float4*)&wp[12];
#pragma unroll
            for (int kw = 0; kw < 5; kw++) {
                float w1 = wf[kw * 3], w2 = wf[kw * 3 + 1], w3 = wf[kw * 3 + 2];
#pragma unroll
                for (int i = 0; i < 16; i++) {
                    float v = xv[kw + i];
                    s[i] += v; q[i] += v * v;
                    z1[i] += w1 * v; z2[i] += w2 * v; z3[i] += w3 * v;
                }
            }
        }
    }

    float gm[16];
    {
        const float* gp = &glds[o * 20];
        *(float4*)&gm[0]  = *(const float4*)&gp[0];
        *(float4*)&gm[4]  = *(const float4*)&gp[4];
        *(float4*)&gm[8]  = *(const float4*)&gp[8];
        *(float4*)&gm[12] = *(const float4*)&gp[12];
    }
    const float C1 = 0.36787944117144233f;
    const float INV = 1.5819767068693265f;
#pragma unroll
    for (int pp = 0; pp < 8; pp++) {
        int pl = cq * 8 + pp;
        if (pl < 15) {
            float aa = 0.f;
#pragma unroll
            for (int e = 0; e < 2; e++) {
                int i = 2 * pp + e;
                float sum = s[i], sq = q[i];
                float gg2 = (sq - sum * sum * (1.f / 75.f)) * (1.f / 74.f);
                float zf[4] = { sum, z1[i], z2[i], z3[i] };
                float qf = 0.f;
#pragma unroll
                for (int f = 0; f < 4; f++) {
                    float acc = 0.f;
#pragma unroll
                    for (int h = 0; h < 4; h++) acc += gm[f * 4 + h] * zf[h];
                    qf += acc * zf[f];
                }
                float err = (sq - qf) / (75.f * gg2);
                aa += (expf(-err) - C1) * INV - 0.5f;
            }
            part[(rw * 15 + pl) * 66 + o] = 0.25f * aa;
        }
    }
    __syncthreads();

    int j = t >> 6;
    float ps = 0.f, pq = 0.f;
    for (int pl = j; pl < 15; pl += 4) {
        float v = part[pl * 66 + o] + part[(15 + pl) * 66 + o];
        g_h1[((b * 30 + r) * 30 + ch * 15 + pl) * 64 + o] = v;
        ps += v; pq += v * v;
    }
    redS[t] = ps; redQ[t] = pq;
    __syncthreads();
    if (t < 64) {
        atomicAdd(&g_s1[t], redS[t] + redS[64 + t] + redS[128 + t] + redS[192 + t]);
        atomicAdd(&g_q1[t], redQ[t] + redQ[64 + t] + redQ[128 + t] + redQ[192 + t]);
    }
}

// -------- bn1-apply + conv2 + bn2 stats --------
// grid 224 = (b, oh28, ocg2); block 256 = oc_l(64) x qtr(4, 7 ow)
__global__ __launch_bounds__(256) void k_conv2(const float* __restrict__ g1,
                                               const float* __restrict__ b1) {
    __shared__ __align__(16) float ws[64 * 148];
    __shared__ __align__(16) float xs[3 * 30 * 64];
    __shared__ float redS[256], redQ[256];
    int blk = blockIdx.x;
    int b = blk / 56, rem = blk % 56, oh = rem >> 1, ocg = rem & 1;
    int t = threadIdx.x;
    int oc_l = t & 63, qtr = t >> 6, owb = qtr * 7;

    // bn1 scale for the 4 ics this thread stages
    int icb = (t & 15) * 4;
    float4 S = *(const float4*)&g_s1[icb], Q = *(const float4*)&g_q1[icb];
    float4 G4 = *(const float4*)&g1[icb], B4 = *(const float4*)&b1[icb];
    float scv[4], shv[4];
    {
        float mm[4] = { S.x, S.y, S.z, S.w }, qq[4] = { Q.x, Q.y, Q.z, Q.w };
        float gg[4] = { G4.x, G4.y, G4.z, G4.w }, bb[4] = { B4.x, B4.y, B4.z, B4.w };
#pragma unroll
        for (int c = 0; c < 4; c++) {
            float m = mm[c] * (1.f / 3600.f);
            float v = qq[c] * (1.f / 3600.f) - m * m;
            scv[c] = gg[c] * rsqrtf(v + 1e-5f);
            shv[c] = bb[c] - m * scv[c];
        }
    }
    // input prefetch (linear: layouts match), 6 f4 guarded
    const float4* src4 = (const float4*)(g_h1 + (b * 900 + oh * 30) * 64);
    float4 xr[6];
#pragma unroll
    for (int k = 0; k < 6; k++) { int i4 = t + k * 256; if (i4 < 1440) xr[k] = src4[i4]; }
    // weight tile 0 prefetch
    const float4* wsrc = (const float4*)g_w2p;
    float4 wreg[9];
#pragma unroll
    for (int k = 0; k < 9; k++) wreg[k] = wsrc[(ocg * 4) * 2304 + k * 256 + t];
    // write input (bn applied) + tile 0
#pragma unroll
    for (int k = 0; k < 6; k++) {
        int i4 = t + k * 256;
        if (i4 < 1440) {
            float4 v;
            v.x = xr[k].x * scv[0] + shv[0]; v.y = xr[k].y * scv[1] + shv[1];
            v.z = xr[k].z * scv[2] + shv[2]; v.w = xr[k].w * scv[3] + shv[3];
            *(float4*)&xs[i4 * 4] = v;
        }
    }
#pragma unroll
    for (int k = 0; k < 9; k++) {
        int idx = k * 256 + t;
        *(float4*)&ws[(idx / 36) * 148 + (idx % 36) * 4] = wreg[k];
    }
    __syncthreads();

    float acc[7] = {0, 0, 0, 0, 0, 0, 0};
    for (int it = 0; it < 4; ++it) {
#pragma unroll
        for (int k = 0; k < 9; k++)
            wreg[k] = wsrc[(ocg * 4 + ((it + 1) & 3)) * 2304 + k * 256 + t];
#pragma unroll
        for (int icq = 0; icq < 4; icq++) {
#pragma unroll
            for (int kh = 0; kh < 3; kh++) {
                const float* wb = &ws[oc_l * 148 + (kh * 4 + icq) * 12];
                float4 w0 = *(const float4*)&wb[0];
                float4 w1 = *(const float4*)&wb[4];
                float4 w2v = *(const float4*)&wb[8];
                float4 xv[9];
#pragma unroll
                for (int k2 = 0; k2 < 9; k2++)
                    xv[k2] = *(const float4*)&xs[(kh * 30 + owb + k2) * 64 + it * 16 + icq * 4];
#pragma unroll
                for (int i = 0; i < 7; i++) {
                    acc[i] += w0.x * xv[i].x + w0.y * xv[i].y + w0.z * xv[i].z + w0.w * xv[i].w
                            + w1.x * xv[i + 1].x + w1.y * xv[i + 1].y + w1.z * xv[i + 1].z + w1.w * xv[i + 1].w
                            + w2v.x * xv[i + 2].x + w2v.y * xv[i + 2].y + w2v.z * xv[i + 2].z + w2v.w * xv[i + 2].w;
                }
            }
        }
        if (it < 3) {
            __syncthreads();
#pragma unroll
            for (int k = 0; k < 9; k++) {
                int idx = k * 256 + t;
                *(float4*)&ws[(idx / 36) * 148 + (idx % 36) * 4] = wreg[k];
            }
            __syncthreads();
        }
    }
    int oc = ocg * 64 + oc_l;
    float ps = 0.f, pq = 0.f;
#pragma unroll
    for (int i = 0; i < 7; i++) {
        int ow = owb + i;
        g_h2[(((b * 14 + (oh >> 1)) * 14 + (ow >> 1)) * 4 + (oh & 1) * 2 + (ow & 1)) * 128 + oc] = acc[i];
        ps += acc[i]; pq += acc[i] * acc[i];
    }
    redS[t] = ps; redQ[t] = pq;
    __syncthreads();
    if (t < 64) {
        atomicAdd(&g_s2[ocg * 64 + t], redS[t] + redS[64 + t] + redS[128 + t] + redS[192 + t]);
        atomicAdd(&g_q2[ocg * 64 + t], redQ[t] + redQ[64 + t] + redQ[128 + t] + redQ[192 + t]);
    }
}

// -------- bn2+relu+avgpool2 + conv3 + bn3 stats --------
// grid 96 = (b, oh12, ocg2); block 256 = oc_l(64) x qtr(4, 3 ow)
__global__ __launch_bounds__(256) void k_conv3(const float* __restrict__ g2,
                                               const float* __restrict__ b2) {
    __shared__ __align__(16) float ws[64 * 148];
    __shared__ __align__(16) float xs[3 * 14 * 128];
    __shared__ float redS[256], redQ[256];
    int blk = blockIdx.x;
    int b = blk / 24, rem = blk % 24, oh = rem >> 1, ocg = rem & 1;
    int t = threadIdx.x;
    int oc_l = t & 63, qtr = t >> 6, owb = qtr * 3;

    int icb = (t & 31) * 4;
    float4 S = *(const float4*)&g_s2[icb], Q = *(const float4*)&g_q2[icb];
    float4 G4 = *(const float4*)&g2[icb], B4 = *(const float4*)&b2[icb];
    float scv[4], shv[4];
    {
        float mm[4] = { S.x, S.y, S.z, S.w }, qq[4] = { Q.x, Q.y, Q.z, Q.w };
        float gg[4] = { G4.x, G4.y, G4.z, G4.w }, bb[4] = { B4.x, B4.y, B4.z, B4.w };
#pragma unroll
        for (int c = 0; c < 4; c++) {
            float m = mm[c] * (1.f / 3136.f);
            float v = qq[c] * (1.f / 3136.f) - m * m;
            scv[c] = gg[c] * rsqrtf(v + 1e-5f);
            shv[c] = bb[c] - m * scv[c];
        }
    }
    // weight tile 0 prefetch
    const float4* wsrc = (const float4*)g_w3p;
    float4 wreg[9];
#pragma unroll
    for (int k = 0; k < 9; k++) wreg[k] = wsrc[(ocg * 8) * 2304 + k * 256 + t];
    // input: 6 guarded f4-elements x 4 loads, pooled
    float4 va[6], vb[6], vc[6], vd[6];
#pragma unroll
    for (int k = 0; k < 6; k++) {
        int i4 = t + k * 256;
        if (i4 < 1344) {
            int px = (i4 >> 5) % 14, rr = i4 / 448;
            const float4* p0 = (const float4*)&g_h2[(((b * 14 + oh + rr) * 14 + px) * 4) * 128 + (i4 & 31) * 4];
            va[k] = p0[0]; vb[k] = p0[32]; vc[k] = p0[64]; vd[k] = p0[96];
        }
    }
#pragma unroll
    for (int k = 0; k < 6; k++) {
        int i4 = t + k * 256;
        if (i4 < 1344) {
            float4 o4;
            o4.x = 0.25f * (fmaxf(va[k].x * scv[0] + shv[0], 0.f) + fmaxf(vb[k].x * scv[0] + shv[0], 0.f)
                          + fmaxf(vc[k].x * scv[0] + shv[0], 0.f) + fmaxf(vd[k].x * scv[0] + shv[0], 0.f));
            o4.y = 0.25f * (fmaxf(va[k].y * scv[1] + shv[1], 0.f) + fmaxf(vb[k].y * scv[1] + shv[1], 0.f)
                          + fmaxf(vc[k].y * scv[1] + shv[1], 0.f) + fmaxf(vd[k].y * scv[1] + shv[1], 0.f));
            o4.z = 0.25f * (fmaxf(va[k].z * scv[2] + shv[2], 0.f) + fmaxf(vb[k].z * scv[2] + shv[2], 0.f)
                          + fmaxf(vc[k].z * scv[2] + shv[2], 0.f) + fmaxf(vd[k].z * scv[2] + shv[2], 0.f));
            o4.w = 0.25f * (fmaxf(va[k].w * scv[3] + shv[3], 0.f) + fmaxf(vb[k].w * scv[3] + shv[3], 0.f)
                          + fmaxf(vc[k].w * scv[3] + shv[3], 0.f) + fmaxf(vd[k].w * scv[3] + shv[3], 0.f));
            *(float4*)&xs[i4 * 4] = o4;
        }
    }
#pragma unroll
    for (int k = 0; k < 9; k++) {
        int idx = k * 256 + t;
        *(float4*)&ws[(idx / 36) * 148 + (idx % 36) * 4] = wreg[k];
    }
    __syncthreads();

    float acc[3] = {0, 0, 0};
    for (int it = 0; it < 8; ++it) {
#pragma unroll
        for (int k = 0; k < 9; k++)
            wreg[k] = wsrc[(ocg * 8 + ((it + 1) & 7)) * 2304 + k * 256 + t];
#pragma unroll
        for (int icq = 0; icq < 4; icq++) {
#pragma unroll
            for (int kh = 0; kh < 3; kh++) {
                const float* wb = &ws[oc_l * 148 + (kh * 4 + icq) * 12];
                float4 w0 = *(const float4*)&wb[0];
                float4 w1 = *(const float4*)&wb[4];
                float4 w2v = *(const float4*)&wb[8];
                float4 xv[5];
#pragma unroll
                for (int k2 = 0; k2 < 5; k2++)
                    xv[k2] = *(const float4*)&xs[(kh * 14 + owb + k2) * 128 + it * 16 + icq * 4];
#pragma unroll
                for (int i = 0; i < 3; i++) {
                    acc[i] += w0.x * xv[i].x + w0.y * xv[i].y + w0.z * xv[i].z + w0.w * xv[i].w
                            + w1.x * xv[i + 1].x + w1.y * xv[i + 1].y + w1.z * xv[i + 1].z + w1.w * xv[i + 1].w
                            + w2v.x * xv[i + 2].x + w2v.y * xv[i + 2].y + w2v.z * xv[i + 2].z + w2v.w * xv[i + 2].w;
                }
            }
        }
        if (it < 7) {
            __syncthreads();
#pragma unroll
            for (int k = 0; k < 9; k++) {
                int idx = k * 256 + t;
                *(float4*)&ws[(idx / 36) * 148 + (idx % 36) * 4] = wreg[k];
            }
            __syncthreads();
        }
    }
    int oc = ocg * 64 + oc_l;
    float ps = 0.f, pq = 0.f;
#pragma unroll
    for (int i = 0; i < 3; i++) {
        int ow = owb + i;
        g_h3[(((b * 6 + (oh >> 1)) * 6 + (ow >> 1)) * 4 + (oh & 1) * 2 + (ow & 1)) * 128 + oc] = acc[i];
        ps += acc[i]; pq += acc[i] * acc[i];
    }
    redS[t] = ps; redQ[t] = pq;
    __syncthreads();
    if (t < 64) {
        atomicAdd(&g_s3[ocg * 64 + t], redS[t] + redS[64 + t] + redS[128 + t] + redS[192 + t]);
        atomicAdd(&g_q3[ocg * 64 + t], redQ[t] + redQ[64 + t] + redQ[128 + t] + redQ[192 + t]);
    }
}

// -------- bn3+relu+maxpool2 + conv4 + bn4 stats --------
// grid 128 = (b, oh4, ocg8); block 256 = oc_l(16) x ow(4) x icq(4=wave)
__global__ __launch_bounds__(256) void k_conv4(const float* __restrict__ g3,
                                               const float* __restrict__ b3) {
    __shared__ __align__(16) float ws[64 * 292];
    __shared__ __align__(16) float xs[3 * 6 * 128];
    __shared__ float red[256];
    int blk = blockIdx.x;
    int b = blk / 32, rem = blk % 32, oh = rem / 8, ocg = rem % 8;
    int t = threadIdx.x;
    int oc_l = t & 15, ow = (t >> 4) & 3, icq = t >> 6;

    int icb = (t & 31) * 4;
    float4 S = *(const float4*)&g_s3[icb], Q = *(const float4*)&g_q3[icb];
    float4 G4 = *(const float4*)&g3[icb], B4 = *(const float4*)&b3[icb];
    float scv[4], shv[4];
    {
        float mm[4] = { S.x, S.y, S.z, S.w }, qq[4] = { Q.x, Q.y, Q.z, Q.w };
        float gg[4] = { G4.x, G4.y, G4.z, G4.w }, bb[4] = { B4.x, B4.y, B4.z, B4.w };
#pragma unroll
        for (int c = 0; c < 4; c++) {
            float m = mm[c] * (1.f / 576.f);
            float v = qq[c] * (1.f / 576.f) - m * m;
            scv[c] = gg[c] * rsqrtf(v + 1e-5f);
            shv[c] = bb[c] - m * scv[c];
        }
    }
    const float4* wsrc = (const float4*)g_w4p + ocg * 4608;
    float4 wreg[18];
#pragma unroll
    for (int k = 0; k < 18; k++) wreg[k] = wsrc[k * 256 + t];
    float4 va[3], vb[3], vc[3], vd[3];
#pragma unroll
    for (int k = 0; k < 3; k++) {
        int i4 = t + k * 256;
        if (i4 < 576) {
            int px = (i4 >> 5) % 6, rr = i4 / 192;
            const float4* p0 = (const float4*)&g_h3[(((b * 6 + oh + rr) * 6 + px) * 4) * 128 + (i4 & 31) * 4];
            va[k] = p0[0]; vb[k] = p0[32]; vc[k] = p0[64]; vd[k] = p0[96];
        }
    }
#pragma unroll
    for (int k = 0; k < 3; k++) {
        int i4 = t + k * 256;
        if (i4 < 576) {
            float4 o4;
            o4.x = fmaxf(fmaxf(fmaxf(va[k].x * scv[0] + shv[0], vb[k].x * scv[0] + shv[0]),
                               fmaxf(vc[k].x * scv[0] + shv[0], vd[k].x * scv[0] + shv[0])), 0.f);
            o4.y = fmaxf(fmaxf(fmaxf(va[k].y * scv[1] + shv[1], vb[k].y * scv[1] + shv[1]),
                               fmaxf(vc[k].y * scv[1] + shv[1], vd[k].y * scv[1] + shv[1])), 0.f);
            o4.z = fmaxf(fmaxf(fmaxf(va[k].z * scv[2] + shv[2], vb[k].z * scv[2] + shv[2]),
                               fmaxf(vc[k].z * scv[2] + shv[2], vd[k].z * scv[2] + shv[2])), 0.f);
            o4.w = fmaxf(fmaxf(fmaxf(va[k].w * scv[3] + shv[3], vb[k].w * scv[3] + shv[3]),
                               fmaxf(vc[k].w * scv[3] + shv[3], vd[k].w * scv[3] + shv[3])), 0.f);
            *(float4*)&xs[i4 * 4] = o4;
        }
    }
#pragma unroll
    for (int k = 0; k < 18; k++) {
        int idx = k * 256 + t;
        *(float4*)&ws[(idx / 72) * 292 + (idx % 72) * 4] = wreg[k];
    }
    __syncthreads();

    float acc = 0.f;
    const float* wbase = &ws[(icq * 16 + oc_l) * 292];
#pragma unroll
    for (int icbq = 0; icbq < 8; icbq++) {
#pragma unroll
        for (int kh = 0; kh < 3; kh++) {
            const float* wb = &wbase[(kh * 8 + icbq) * 12];
            float4 w0 = *(const float4*)&wb[0];
            float4 w1 = *(const float4*)&wb[4];
            float4 w2v = *(const float4*)&wb[8];
            float4 x0 = *(const float4*)&xs[(kh * 6 + ow) * 128 + icq * 32 + icbq * 4];
            float4 x1 = *(const float4*)&xs[(kh * 6 + ow + 1) * 128 + icq * 32 + icbq * 4];
            float4 x2 = *(const float4*)&xs[(kh * 6 + ow + 2) * 128 + icq * 32 + icbq * 4];
            acc += w0.x * x0.x + w0.y * x0.y + w0.z * x0.z + w0.w * x0.w
                 + w1.x * x1.x + w1.y * x1.y + w1.z * x1.z + w1.w * x1.w
                 + w2v.x * x2.x + w2v.y * x2.y + w2v.z * x2.z + w2v.w * x2.w;
        }
    }
    red[t] = acc;
    __syncthreads();
    if (t < 64) {
        float v = red[t] + red[t + 64] + red[t + 128] + red[t + 192];
        int oc = ocg * 16 + (t & 15);
        g_h4[((b * 4 + oh) * 4 + (t >> 4)) * 128 + oc] = v;
        float ps = v + __shfl_xor(v, 16);  ps += __shfl_xor(ps, 32);
        float pv = v * v;
        float pq = pv + __shfl_xor(pv, 16); pq += __shfl_xor(pq, 32);
        if (t < 16) { atomicAdd(&g_s4[ocg * 16 + t], ps); atomicAdd(&g_q4[ocg * 16 + t], pq); }
    }
}

// ------- bn4+relu+maxpool4 + FC -------
__global__ __launch_bounds__(256) void k_final(const float* __restrict__ g4,
                                               const float* __restrict__ b4,
                                               const float* __restrict__ fcw,
                                               const float* __restrict__ fcb,
                                               float* __restrict__ out) {
    __shared__ float sc[128], sh[128];
    __shared__ float pooled[4][128];
    int t = threadIdx.x;
    if (t < 128) {
        float m = g_s4[t] * (1.f / 64.f);
        float v = g_q4[t] * (1.f / 64.f) - m * m;
        float rs = rsqrtf(v + 1e-5f);
        sc[t] = g4[t] * rs; sh[t] = b4[t] - m * sc[t];
    }
    __syncthreads();
    for (int item = t; item < 512; item += 256) {
        int b = item >> 7, oc = item & 127;
        float s = sc[oc], h = sh[oc];
        float mx = 0.f;
#pragma unroll
        for (int k = 0; k < 16; k++) mx = fmaxf(mx, g_h4[(b * 16 + k) * 128 + oc] * s + h);
        pooled[b][oc] = mx;
    }
    __syncthreads();
    if (t < 20) {
        int b = t / 5, cls = t % 5;
        float acc = fcb[cls];
        const float* w = &fcw[cls * 128];
        for (int oc = 0; oc < 128; oc++) acc += pooled[b][oc] * w[oc];
        out[b * 5 + cls] = acc;
    }
}

extern "C" void kernel_launch(void* const* d_in, const int* in_sizes, int n_in,
                              void* d_out, int out_size, void* d_ws, size_t ws_size,
                              hipStream_t stream) {
    (void)in_sizes; (void)n_in; (void)out_size; (void)d_ws; (void)ws_size;
    const float* x     = (const float*)d_in[0];
    const float* srn_w = (const float*)d_in[1];
    const float* w2    = (const float*)d_in[2];
    const float* w3    = (const float*)d_in[4];
    const float* w4    = (const float*)d_in[6];
    const float* g1 = (const float*)d_in[8];  const float* b1 = (const float*)d_in[9];
    const float* g2 = (const float*)d_in[10]; const float* b2 = (const float*)d_in[11];
    const float* g3 = (const float*)d_in[12]; const float* b3 = (const float*)d_in[13];
    const float* g4 = (const float*)d_in[14]; const float* b4 = (const float*)d_in[15];
    const float* fcw = (const float*)d_in[16]; const float* fcb = (const float*)d_in[17];
    float* out = (float*)d_out;

    k_prep <<<dim3(128), dim3(256), 0, stream>>>(srn_w, w2, w3, w4);
    k_srn  <<<dim3(240), dim3(256), 0, stream>>>(x);
    k_conv2<<<dim3(224), dim3(256), 0, stream>>>(g1, b1);
    k_conv3<<<dim3(96),  dim3(256), 0, stream>>>(g2, b2);
    k_conv4<<<dim3(128), dim3(256), 0, stream>>>(g3, b3);
    k_final<<<dim3(1),   dim3(256), 0, stream>>>(g4, b4, fcw, fcb, out);
}

// Round 4
// 115.434 us; speedup vs baseline: 1.9804x; 1.4575x over previous
//
#include <hip/hip_runtime.h>
#include <math.h>

// ---------------- persistent device scratch ----------------
__device__ __align__(16) float g_G[64 * 16];     // (X^T X)^-1 per SRN channel
__device__ __align__(16) float g_Wp[64 * 240];   // srn weights [o][15 rows][16]
__device__ __align__(16) float g_w2p[9 * 2304 * 4];   // conv2 staging-order (+1 pad tile)
__device__ __align__(16) float g_w3p[17 * 2304 * 4];  // conv3 staging-order (+1 pad tile)
__device__ __align__(16) float g_w4p[8 * 4608 * 4];   // conv4 staging-order
__device__ float g_s1[64],  g_q1[64];
__device__ float g_s2[128], g_q2[128];
__device__ float g_s3[128], g_q3[128];
__device__ float g_s4[128], g_q4[128];
__device__ __align__(16) float g_h1[4 * 30 * 30 * 64];   // [b][r][c][ic]
__device__ __align__(16) float g_h2[4 * 14 * 14 * 4 * 128]; // pool-pair layout
__device__ __align__(16) float g_h3[4 * 6 * 6 * 4 * 128];   // pool-pair layout
__device__ __align__(16) float g_h4[4 * 16 * 128];

// ------------- prep: zero stats + Gram inverse + weight repacks -------------
__global__ void k_prep(const float* __restrict__ srn_w, const float* __restrict__ w2,
                       const float* __restrict__ w3, const float* __restrict__ w4) {
    int t = threadIdx.x, bid = blockIdx.x;
    int gid = bid * 256 + t, gstride = 128 * 256;
    for (int i = gid; i < 14400; i += gstride) {
        int o = i / 225, j = i % 225, row = j / 15, col = j % 15;
        g_Wp[o * 240 + row * 16 + col] = srn_w[i];
    }
    // conv2: [blk=ocg*4+it][oc_l][sl=(kh*4+icq)*3+kw][c=ic%4]
    for (int j = gid; j < 73728; j += gstride) {
        int c = j & 3, s4 = j >> 2;
        int sl = s4 % 36, tmp = s4 / 36, oc_l = tmp & 63, blk = tmp >> 6;
        int it = blk & 3, ocg = blk >> 2;
        int kw = sl % 3, icq = (sl / 3) & 3, kh = sl / 12;
        int ic = it * 16 + icq * 4 + c;
        g_w2p[j] = w2[((ocg * 64 + oc_l) * 64 + ic) * 9 + kh * 3 + kw];
    }
    // conv3: [blk=ocg*8+it][oc_l][sl][c]
    for (int j = gid; j < 147456; j += gstride) {
        int c = j & 3, s4 = j >> 2;
        int sl = s4 % 36, tmp = s4 / 36, oc_l = tmp & 63, blk = tmp >> 6;
        int it = blk & 7, ocg = blk >> 3;
        int kw = sl % 3, icq = (sl / 3) & 3, kh = sl / 12;
        int ic = it * 16 + icq * 4 + c;
        g_w3p[j] = w3[((ocg * 64 + oc_l) * 128 + ic) * 9 + kh * 3 + kw];
    }
    // conv4: [ocg][icq][oc_l][sl=(kh*8+icb)*3+kw][c]
    for (int j = gid; j < 147456; j += gstride) {
        int c = j & 3, s4 = j >> 2;
        int sl = s4 % 72, tmp = s4 / 72, oc_l = tmp & 15, blkq = tmp >> 4;
        int icq = blkq & 3, ocg = blkq >> 2;
        int kw = sl % 3, icb = (sl / 3) & 7, kh = sl / 24;
        int ic = icq * 32 + icb * 4 + c;
        g_w4p[j] = w4[((ocg * 16 + oc_l) * 128 + ic) * 9 + kh * 3 + kw];
    }
    if (bid == 0) {
        if (t < 64) { g_s1[t] = 0.f; g_q1[t] = 0.f; }
        if (t < 128) {
            g_s2[t] = 0.f; g_q2[t] = 0.f;
            g_s3[t] = 0.f; g_q3[t] = 0.f;
            g_s4[t] = 0.f; g_q4[t] = 0.f;
        }
        if (t < 64) {
            int o = t;
            const float* w = srn_w + o * 225;
            float c01 = 0, c02 = 0, c03 = 0, c11 = 0, c12 = 0, c13 = 0,
                  c22 = 0, c23 = 0, c33 = 0;
            for (int n = 0; n < 75; n++) {
                float w1 = w[n * 3 + 0], w2v = w[n * 3 + 1], w3v = w[n * 3 + 2];
                c01 += w1; c02 += w2v; c03 += w3v;
                c11 += w1 * w1; c12 += w1 * w2v; c13 += w1 * w3v;
                c22 += w2v * w2v; c23 += w2v * w3v; c33 += w3v * w3v;
            }
            float A[4][8];
            A[0][0] = 75.f; A[0][1] = c01; A[0][2] = c02; A[0][3] = c03;
            A[1][0] = c01;  A[1][1] = c11; A[1][2] = c12; A[1][3] = c13;
            A[2][0] = c02;  A[2][1] = c12; A[2][2] = c22; A[2][3] = c23;
            A[3][0] = c03;  A[3][1] = c13; A[3][2] = c23; A[3][3] = c33;
            for (int i = 0; i < 4; i++)
                for (int j = 0; j < 4; j++) A[i][4 + j] = (i == j) ? 1.f : 0.f;
            for (int p = 0; p < 4; p++) {
                float ip = 1.f / A[p][p];
                for (int j = 0; j < 8; j++) A[p][j] *= ip;
                for (int i = 0; i < 4; i++) if (i != p) {
                    float f = A[i][p];
                    for (int j = 0; j < 8; j++) A[i][j] -= f * A[p][j];
                }
            }
            for (int i = 0; i < 4; i++)
                for (int j = 0; j < 4; j++) g_G[o * 16 + i * 4 + j] = A[i][4 + j];
        }
    }
}

// ---------------- SRN + avgpool2 + bn1 stats ----------------
__global__ __launch_bounds__(256) void k_srn(const float* __restrict__ x) {
    __shared__ __align__(16) float wlds[64 * 244];
    __shared__ __align__(16) float glds[64 * 20];
    __shared__ float xsm[648];
    __shared__ float part[2 * 15 * 66];
    __shared__ float redS[256], redQ[256];
    int blk = blockIdx.x;
    int b = blk / 60, rem = blk % 60, r = rem >> 1, ch = rem & 1;
    int t = threadIdx.x;

    float4 wreg[15];
#pragma unroll
    for (int k = 0; k < 15; k++) wreg[k] = ((const float4*)g_Wp)[k * 256 + t];
    float4 greg = ((const float4*)g_G)[t];
    float xr[3];
#pragma unroll
    for (int k = 0; k < 3; k++) {
        int i = t + k * 256;
        if (i < 648) {
            int c = i / 216, rm = i % 216, rr = rm / 36, col = rm % 36;
            int gc = ch * 30 + col; if (gc > 63) gc = 63;
            xr[k] = x[((b * 3 + c) * 64 + (2 * r + rr)) * 64 + gc];
        }
    }
#pragma unroll
    for (int k = 0; k < 15; k++) {
        int idx = k * 256 + t;
        *(float4*)&wlds[(idx / 60) * 244 + (idx % 60) * 4] = wreg[k];
    }
    *(float4*)&glds[(t >> 2) * 20 + (t & 3) * 4] = greg;
#pragma unroll
    for (int k = 0; k < 3; k++) { int i = t + k * 256; if (i < 648) xsm[i] = xr[k]; }
    __syncthreads();

    int w = t >> 6, o = t & 63;
    int rw = w & 1, cq = w >> 1, base = cq * 16;

    float z1[16], z2[16], z3[16], s[16], q[16];
#pragma unroll
    for (int i = 0; i < 16; i++) { z1[i] = 0; z2[i] = 0; z3[i] = 0; s[i] = 0; q[i] = 0; }

    for (int c = 0; c < 3; c++) {
#pragma unroll
        for (int kh = 0; kh < 5; kh++) {
            float xv[20];
#pragma unroll
            for (int k = 0; k < 20; k++) xv[k] = xsm[(c * 6 + rw + kh) * 36 + base + k];
            float wf[16];
            const float* wp = &wlds[o * 244 + (c * 5 + kh) * 16];
            *(float4*)&wf[0]  = *(const float4*)&wp[0];
            *(float4*)&wf[4]  = *(const float4*)&wp[4];
            *(float4*)&wf[8]  = *(const float4*)&wp[8];
            *(float4*)&wf[12] = *(const float4*)&wp[12];
#pragma unroll
            for (int kw = 0; kw < 5; kw++) {
                float w1 = wf[kw * 3], w2 = wf[kw * 3 + 1], w3 = wf[kw * 3 + 2];
#pragma unroll
                for (int i = 0; i < 16; i++) {
                    float v = xv[kw + i];
                    s[i] += v; q[i] += v * v;
                    z1[i] += w1 * v; z2[i] += w2 * v; z3[i] += w3 * v;
                }
            }
        }
    }

    float gm[16];
    {
        const float* gp = &glds[o * 20];
        *(float4*)&gm[0]  = *(const float4*)&gp[0];
        *(float4*)&gm[4]  = *(const float4*)&gp[4];
        *(float4*)&gm[8]  = *(const float4*)&gp[8];
        *(float4*)&gm[12] = *(const float4*)&gp[12];
    }
    const float C1 = 0.36787944117144233f;
    const float INV = 1.5819767068693265f;
#pragma unroll
    for (int pp = 0; pp < 8; pp++) {
        int pl = cq * 8 + pp;
        if (pl < 15) {
            float aa = 0.f;
#pragma unroll
            for (int e = 0; e < 2; e++) {
                int i = 2 * pp + e;
                float sum = s[i], sq = q[i];
                float gg2 = (sq - sum * sum * (1.f / 75.f)) * (1.f / 74.f);
                float zf[4] = { sum, z1[i], z2[i], z3[i] };
                float qf = 0.f;
#pragma unroll
                for (int f = 0; f < 4; f++) {
                    float acc = 0.f;
#pragma unroll
                    for (int h = 0; h < 4; h++) acc += gm[f * 4 + h] * zf[h];
                    qf += acc * zf[f];
                }
                float err = (sq - qf) / (75.f * gg2);
                aa += (expf(-err) - C1) * INV - 0.5f;
            }
            part[(rw * 15 + pl) * 66 + o] = 0.25f * aa;
        }
    }
    __syncthreads();

    int j = t >> 6;
    float ps = 0.f, pq = 0.f;
    for (int pl = j; pl < 15; pl += 4) {
        float v = part[pl * 66 + o] + part[(15 + pl) * 66 + o];
        g_h1[((b * 30 + r) * 30 + ch * 15 + pl) * 64 + o] = v;
        ps += v; pq += v * v;
    }
    redS[t] = ps; redQ[t] = pq;
    __syncthreads();
    if (t < 64) {
        atomicAdd(&g_s1[t], redS[t] + redS[64 + t] + redS[128 + t] + redS[192 + t]);
        atomicAdd(&g_q1[t], redQ[t] + redQ[64 + t] + redQ[128 + t] + redQ[192 + t]);
    }
}

// -------- bn1-apply + conv2 + bn2 stats --------
// grid 224 = (b, oh28, ocg2); block 256 = oc_l(64) x qtr(4, 7 ow)
// Spill-safe: unroll-1 icq loop + sliding 3-reg x window.
__global__ __launch_bounds__(256) void k_conv2(const float* __restrict__ g1,
                                               const float* __restrict__ b1) {
    __shared__ __align__(16) float ws[64 * 148];
    __shared__ __align__(16) float xs[3 * 30 * 64];
    __shared__ float redS[256], redQ[256];
    int blk = blockIdx.x;
    int b = blk / 56, rem = blk % 56, oh = rem >> 1, ocg = rem & 1;
    int t = threadIdx.x;
    int oc_l = t & 63, qtr = t >> 6, owb = qtr * 7;

    {   // staging: bn1 scales + input + weight tile 0
        int icb = (t & 15) * 4;
        float4 S = *(const float4*)&g_s1[icb], Q = *(const float4*)&g_q1[icb];
        float4 G4 = *(const float4*)&g1[icb], B4 = *(const float4*)&b1[icb];
        float scv[4], shv[4];
        float mm[4] = { S.x, S.y, S.z, S.w }, qq[4] = { Q.x, Q.y, Q.z, Q.w };
        float gg[4] = { G4.x, G4.y, G4.z, G4.w }, bb[4] = { B4.x, B4.y, B4.z, B4.w };
#pragma unroll
        for (int c = 0; c < 4; c++) {
            float m = mm[c] * (1.f / 3600.f);
            float v = qq[c] * (1.f / 3600.f) - m * m;
            scv[c] = gg[c] * rsqrtf(v + 1e-5f);
            shv[c] = bb[c] - m * scv[c];
        }
        const float4* src4 = (const float4*)(g_h1 + (b * 900 + oh * 30) * 64);
        float4 xr[6];
#pragma unroll
        for (int k = 0; k < 6; k++) { int i4 = t + k * 256; if (i4 < 1440) xr[k] = src4[i4]; }
        const float4* wsrc0 = (const float4*)g_w2p;
        float4 wreg[9];
#pragma unroll
        for (int k = 0; k < 9; k++) wreg[k] = wsrc0[(ocg * 4) * 2304 + k * 256 + t];
#pragma unroll
        for (int k = 0; k < 6; k++) {
            int i4 = t + k * 256;
            if (i4 < 1440) {
                float4 v;
                v.x = xr[k].x * scv[0] + shv[0]; v.y = xr[k].y * scv[1] + shv[1];
                v.z = xr[k].z * scv[2] + shv[2]; v.w = xr[k].w * scv[3] + shv[3];
                *(float4*)&xs[i4 * 4] = v;
            }
        }
#pragma unroll
        for (int k = 0; k < 9; k++) {
            int idx = k * 256 + t;
            *(float4*)&ws[(idx / 36) * 148 + (idx % 36) * 4] = wreg[k];
        }
    }
    __syncthreads();

    float acc[7] = {0, 0, 0, 0, 0, 0, 0};
    const float4* wsrc = (const float4*)g_w2p + (ocg * 4) * 2304;
    for (int it = 0; it < 4; ++it) {
        float4 wreg[9];
        if (it < 3) {
#pragma unroll
            for (int k = 0; k < 9; k++) wreg[k] = wsrc[(it + 1) * 2304 + k * 256 + t];
        }
#pragma unroll 1
        for (int icq = 0; icq < 4; icq++) {
            int xoff = it * 16 + icq * 4;
#pragma unroll
            for (int kh = 0; kh < 3; kh++) {
                const float* wb = &ws[oc_l * 148 + (kh * 4 + icq) * 12];
                float4 w0 = *(const float4*)&wb[0];
                float4 w1 = *(const float4*)&wb[4];
                float4 w2v = *(const float4*)&wb[8];
                const float* xrow = &xs[(kh * 30 + owb) * 64 + xoff];
                float4 x0 = *(const float4*)&xrow[0];
                float4 x1 = *(const float4*)&xrow[64];
#pragma unroll
                for (int i = 0; i < 7; i++) {
                    float4 x2 = *(const float4*)&xrow[(i + 2) * 64];
                    acc[i] += w0.x * x0.x + w0.y * x0.y + w0.z * x0.z + w0.w * x0.w
                            + w1.x * x1.x + w1.y * x1.y + w1.z * x1.z + w1.w * x1.w
                            + w2v.x * x2.x + w2v.y * x2.y + w2v.z * x2.z + w2v.w * x2.w;
                    x0 = x1; x1 = x2;
                }
            }
        }
        if (it < 3) {
            __syncthreads();
#pragma unroll
            for (int k = 0; k < 9; k++) {
                int idx = k * 256 + t;
                *(float4*)&ws[(idx / 36) * 148 + (idx % 36) * 4] = wreg[k];
            }
            __syncthreads();
        }
    }
    int oc = ocg * 64 + oc_l;
    float ps = 0.f, pq = 0.f;
#pragma unroll
    for (int i = 0; i < 7; i++) {
        int ow = owb + i;
        g_h2[(((b * 14 + (oh >> 1)) * 14 + (ow >> 1)) * 4 + (oh & 1) * 2 + (ow & 1)) * 128 + oc] = acc[i];
        ps += acc[i]; pq += acc[i] * acc[i];
    }
    redS[t] = ps; redQ[t] = pq;
    __syncthreads();
    if (t < 64) {
        atomicAdd(&g_s2[ocg * 64 + t], redS[t] + redS[64 + t] + redS[128 + t] + redS[192 + t]);
        atomicAdd(&g_q2[ocg * 64 + t], redQ[t] + redQ[64 + t] + redQ[128 + t] + redQ[192 + t]);
    }
}

// -------- bn2+relu+avgpool2 + conv3 + bn3 stats --------
// grid 96 = (b, oh12, ocg2); block 256 = oc_l(64) x qtr(4, 3 ow)
__global__ __launch_bounds__(256) void k_conv3(const float* __restrict__ g2,
                                               const float* __restrict__ b2) {
    __shared__ __align__(16) float ws[64 * 148];
    __shared__ __align__(16) float xs[3 * 14 * 128];
    __shared__ float redS[256], redQ[256];
    int blk = blockIdx.x;
    int b = blk / 24, rem = blk % 24, oh = rem >> 1, ocg = rem & 1;
    int t = threadIdx.x;
    int oc_l = t & 63, qtr = t >> 6, owb = qtr * 3;

    {
        int icb = (t & 31) * 4;
        float4 S = *(const float4*)&g_s2[icb], Q = *(const float4*)&g_q2[icb];
        float4 G4 = *(const float4*)&g2[icb], B4 = *(const float4*)&b2[icb];
        float scv[4], shv[4];
        float mm[4] = { S.x, S.y, S.z, S.w }, qq[4] = { Q.x, Q.y, Q.z, Q.w };
        float gg[4] = { G4.x, G4.y, G4.z, G4.w }, bb[4] = { B4.x, B4.y, B4.z, B4.w };
#pragma unroll
        for (int c = 0; c < 4; c++) {
            float m = mm[c] * (1.f / 3136.f);
            float v = qq[c] * (1.f / 3136.f) - m * m;
            scv[c] = gg[c] * rsqrtf(v + 1e-5f);
            shv[c] = bb[c] - m * scv[c];
        }
        const float4* wsrc0 = (const float4*)g_w3p;
        float4 wreg[9];
#pragma unroll
        for (int k = 0; k < 9; k++) wreg[k] = wsrc0[(ocg * 8) * 2304 + k * 256 + t];
        float4 va[6], vb[6], vc[6], vd[6];
#pragma unroll
        for (int k = 0; k < 6; k++) {
            int i4 = t + k * 256;
            if (i4 < 1344) {
                int px = (i4 >> 5) % 14, rr = i4 / 448;
                const float4* p0 = (const float4*)&g_h2[(((b * 14 + oh + rr) * 14 + px) * 4) * 128 + (i4 & 31) * 4];
                va[k] = p0[0]; vb[k] = p0[32]; vc[k] = p0[64]; vd[k] = p0[96];
            }
        }
#pragma unroll
        for (int k = 0; k < 9; k++) {
            int idx = k * 256 + t;
            *(float4*)&ws[(idx / 36) * 148 + (idx % 36) * 4] = wreg[k];
        }
#pragma unroll
        for (int k = 0; k < 6; k++) {
            int i4 = t + k * 256;
            if (i4 < 1344) {
                float4 o4;
                o4.x = 0.25f * (fmaxf(va[k].x * scv[0] + shv[0], 0.f) + fmaxf(vb[k].x * scv[0] + shv[0], 0.f)
                              + fmaxf(vc[k].x * scv[0] + shv[0], 0.f) + fmaxf(vd[k].x * scv[0] + shv[0], 0.f));
                o4.y = 0.25f * (fmaxf(va[k].y * scv[1] + shv[1], 0.f) + fmaxf(vb[k].y * scv[1] + shv[1], 0.f)
                              + fmaxf(vc[k].y * scv[1] + shv[1], 0.f) + fmaxf(vd[k].y * scv[1] + shv[1], 0.f));
                o4.z = 0.25f * (fmaxf(va[k].z * scv[2] + shv[2], 0.f) + fmaxf(vb[k].z * scv[2] + shv[2], 0.f)
                              + fmaxf(vc[k].z * scv[2] + shv[2], 0.f) + fmaxf(vd[k].z * scv[2] + shv[2], 0.f));
                o4.w = 0.25f * (fmaxf(va[k].w * scv[3] + shv[3], 0.f) + fmaxf(vb[k].w * scv[3] + shv[3], 0.f)
                              + fmaxf(vc[k].w * scv[3] + shv[3], 0.f) + fmaxf(vd[k].w * scv[3] + shv[3], 0.f));
                *(float4*)&xs[i4 * 4] = o4;
            }
        }
    }
    __syncthreads();

    float acc[3] = {0, 0, 0};
    const float4* wsrc = (const float4*)g_w3p + (ocg * 8) * 2304;
    for (int it = 0; it < 8; ++it) {
        float4 wreg[9];
        if (it < 7) {
#pragma unroll
            for (int k = 0; k < 9; k++) wreg[k] = wsrc[(it + 1) * 2304 + k * 256 + t];
        }
#pragma unroll 1
        for (int icq = 0; icq < 4; icq++) {
            int xoff = it * 16 + icq * 4;
#pragma unroll
            for (int kh = 0; kh < 3; kh++) {
                const float* wb = &ws[oc_l * 148 + (kh * 4 + icq) * 12];
                float4 w0 = *(const float4*)&wb[0];
                float4 w1 = *(const float4*)&wb[4];
                float4 w2v = *(const float4*)&wb[8];
                const float* xrow = &xs[(kh * 14 + owb) * 128 + xoff];
                float4 x0 = *(const float4*)&xrow[0];
                float4 x1 = *(const float4*)&xrow[128];
#pragma unroll
                for (int i = 0; i < 3; i++) {
                    float4 x2 = *(const float4*)&xrow[(i + 2) * 128];
                    acc[i] += w0.x * x0.x + w0.y * x0.y + w0.z * x0.z + w0.w * x0.w
                            + w1.x * x1.x + w1.y * x1.y + w1.z * x1.z + w1.w * x1.w
                            + w2v.x * x2.x + w2v.y * x2.y + w2v.z * x2.z + w2v.w * x2.w;
                    x0 = x1; x1 = x2;
                }
            }
        }
        if (it < 7) {
            __syncthreads();
#pragma unroll
            for (int k = 0; k < 9; k++) {
                int idx = k * 256 + t;
                *(float4*)&ws[(idx / 36) * 148 + (idx % 36) * 4] = wreg[k];
            }
            __syncthreads();
        }
    }
    int oc = ocg * 64 + oc_l;
    float ps = 0.f, pq = 0.f;
#pragma unroll
    for (int i = 0; i < 3; i++) {
        int ow = owb + i;
        g_h3[(((b * 6 + (oh >> 1)) * 6 + (ow >> 1)) * 4 + (oh & 1) * 2 + (ow & 1)) * 128 + oc] = acc[i];
        ps += acc[i]; pq += acc[i] * acc[i];
    }
    redS[t] = ps; redQ[t] = pq;
    __syncthreads();
    if (t < 64) {
        atomicAdd(&g_s3[ocg * 64 + t], redS[t] + redS[64 + t] + redS[128 + t] + redS[192 + t]);
        atomicAdd(&g_q3[ocg * 64 + t], redQ[t] + redQ[64 + t] + redQ[128 + t] + redQ[192 + t]);
    }
}

// -------- bn3+relu+maxpool2 + conv4 + bn4 stats --------
// grid 128 = (b, oh4, ocg8); block 256 = oc_l(16) x ow(4) x icq(4=wave)
__global__ __launch_bounds__(256) void k_conv4(const float* __restrict__ g3,
                                               const float* __restrict__ b3) {
    __shared__ __align__(16) float ws[64 * 292];
    __shared__ __align__(16) float xs[3 * 6 * 128];
    __shared__ float red[256];
    int blk = blockIdx.x;
    int b = blk / 32, rem = blk % 32, oh = rem / 8, ocg = rem % 8;
    int t = threadIdx.x;
    int oc_l = t & 15, ow = (t >> 4) & 3, icq = t >> 6;

    {
        int icb = (t & 31) * 4;
        float4 S = *(const float4*)&g_s3[icb], Q = *(const float4*)&g_q3[icb];
        float4 G4 = *(const float4*)&g3[icb], B4 = *(const float4*)&b3[icb];
        float scv[4], shv[4];
        float mm[4] = { S.x, S.y, S.z, S.w }, qq[4] = { Q.x, Q.y, Q.z, Q.w };
        float gg[4] = { G4.x, G4.y, G4.z, G4.w }, bb[4] = { B4.x, B4.y, B4.z, B4.w };
#pragma unroll
        for (int c = 0; c < 4; c++) {
            float m = mm[c] * (1.f / 576.f);
            float v = qq[c] * (1.f / 576.f) - m * m;
            scv[c] = gg[c] * rsqrtf(v + 1e-5f);
            shv[c] = bb[c] - m * scv[c];
        }
        const float4* wsrc = (const float4*)g_w4p + ocg * 4608;
        float4 wreg[18];
#pragma unroll
        for (int k = 0; k < 18; k++) wreg[k] = wsrc[k * 256 + t];
        float4 va[3], vb[3], vc[3], vd[3];
#pragma unroll
        for (int k = 0; k < 3; k++) {
            int i4 = t + k * 256;
            if (i4 < 576) {
                int px = (i4 >> 5) % 6, rr = i4 / 192;
                const float4* p0 = (const float4*)&g_h3[(((b * 6 + oh + rr) * 6 + px) * 4) * 128 + (i4 & 31) * 4];
                va[k] = p0[0]; vb[k] = p0[32]; vc[k] = p0[64]; vd[k] = p0[96];
            }
        }
        // write weights to LDS first: kills 72 wreg registers before pooling math
#pragma unroll
        for (int k = 0; k < 18; k++) {
            int idx = k * 256 + t;
            *(float4*)&ws[(idx / 72) * 292 + (idx % 72) * 4] = wreg[k];
        }
#pragma unroll
        for (int k = 0; k < 3; k++) {
            int i4 = t + k * 256;
            if (i4 < 576) {
                float4 o4;
                o4.x = fmaxf(fmaxf(fmaxf(va[k].x * scv[0] + shv[0], vb[k].x * scv[0] + shv[0]),
                                   fmaxf(vc[k].x * scv[0] + shv[0], vd[k].x * scv[0] + shv[0])), 0.f);
                o4.y = fmaxf(fmaxf(fmaxf(va[k].y * scv[1] + shv[1], vb[k].y * scv[1] + shv[1]),
                                   fmaxf(vc[k].y * scv[1] + shv[1], vd[k].y * scv[1] + shv[1])), 0.f);
                o4.z = fmaxf(fmaxf(fmaxf(va[k].z * scv[2] + shv[2], vb[k].z * scv[2] + shv[2]),
                                   fmaxf(vc[k].z * scv[2] + shv[2], vd[k].z * scv[2] + shv[2])), 0.f);
                o4.w = fmaxf(fmaxf(fmaxf(va[k].w * scv[3] + shv[3], vb[k].w * scv[3] + shv[3]),
                                   fmaxf(vc[k].w * scv[3] + shv[3], vd[k].w * scv[3] + shv[3])), 0.f);
                *(float4*)&xs[i4 * 4] = o4;
            }
        }
    }
    __syncthreads();

    float acc = 0.f;
    const float* wbase = &ws[(icq * 16 + oc_l) * 292];
#pragma unroll 1
    for (int icbq = 0; icbq < 8; icbq++) {
#pragma unroll
        for (int kh = 0; kh < 3; kh++) {
            const float* wb = &wbase[(kh * 8 + icbq) * 12];
            float4 w0 = *(const float4*)&wb[0];
            float4 w1 = *(const float4*)&wb[4];
            float4 w2v = *(const float4*)&wb[8];
            float4 x0 = *(const float4*)&xs[(kh * 6 + ow) * 128 + icq * 32 + icbq * 4];
            float4 x1 = *(const float4*)&xs[(kh * 6 + ow + 1) * 128 + icq * 32 + icbq * 4];
            float4 x2 = *(const float4*)&xs[(kh * 6 + ow + 2) * 128 + icq * 32 + icbq * 4];
            acc += w0.x * x0.x + w0.y * x0.y + w0.z * x0.z + w0.w * x0.w
                 + w1.x * x1.x + w1.y * x1.y + w1.z * x1.z + w1.w * x1.w
                 + w2v.x * x2.x + w2v.y * x2.y + w2v.z * x2.z + w2v.w * x2.w;
        }
    }
    red[t] = acc;
    __syncthreads();
    if (t < 64) {
        float v = red[t] + red[t + 64] + red[t + 128] + red[t + 192];
        int oc = ocg * 16 + (t & 15);
        g_h4[((b * 4 + oh) * 4 + (t >> 4)) * 128 + oc] = v;
        float ps = v + __shfl_xor(v, 16);  ps += __shfl_xor(ps, 32);
        float pv = v * v;
        float pq = pv + __shfl_xor(pv, 16); pq += __shfl_xor(pq, 32);
        if (t < 16) { atomicAdd(&g_s4[ocg * 16 + t], ps); atomicAdd(&g_q4[ocg * 16 + t], pq); }
    }
}

// ------- bn4+relu+maxpool4 + FC -------
__global__ __launch_bounds__(256) void k_final(const float* __restrict__ g4,
                                               const float* __restrict__ b4,
                                               const float* __restrict__ fcw,
                                               const float* __restrict__ fcb,
                                               float* __restrict__ out) {
    __shared__ float sc[128], sh[128];
    __shared__ float pooled[4][128];
    int t = threadIdx.x;
    if (t < 128) {
        float m = g_s4[t] * (1.f / 64.f);
        float v = g_q4[t] * (1.f / 64.f) - m * m;
        float rs = rsqrtf(v + 1e-5f);
        sc[t] = g4[t] * rs; sh[t] = b4[t] - m * sc[t];
    }
    __syncthreads();
    for (int item = t; item < 512; item += 256) {
        int b = item >> 7, oc = item & 127;
        float s = sc[oc], h = sh[oc];
        float mx = 0.f;
#pragma unroll
        for (int k = 0; k < 16; k++) mx = fmaxf(mx, g_h4[(b * 16 + k) * 128 + oc] * s + h);
        pooled[b][oc] = mx;
    }
    __syncthreads();
    if (t < 20) {
        int b = t / 5, cls = t % 5;
        float acc = fcb[cls];
        const float* w = &fcw[cls * 128];
        for (int oc = 0; oc < 128; oc++) acc += pooled[b][oc] * w[oc];
        out[b * 5 + cls] = acc;
    }
}

extern "C" void kernel_launch(void* const* d_in, const int* in_sizes, int n_in,
                              void* d_out, int out_size, void* d_ws, size_t ws_size,
                              hipStream_t stream) {
    (void)in_sizes; (void)n_in; (void)out_size; (void)d_ws; (void)ws_size;
    const float* x     = (const float*)d_in[0];
    const float* srn_w = (const float*)d_in[1];
    const float* w2    = (const float*)d_in[2];
    const float* w3    = (const float*)d_in[4];
    const float* w4    = (const float*)d_in[6];
    const float* g1 = (const float*)d_in[8];  const float* b1 = (const float*)d_in[9];
    const float* g2 = (const float*)d_in[10]; const float* b2 = (const float*)d_in[11];
    const float* g3 = (const float*)d_in[12]; const float* b3 = (const float*)d_in[13];
    const float* g4 = (const float*)d_in[14]; const float* b4 = (const float*)d_in[15];
    const float* fcw = (const float*)d_in[16]; const float* fcb = (const float*)d_in[17];
    float* out = (float*)d_out;

    k_prep <<<dim3(128), dim3(256), 0, stream>>>(srn_w, w2, w3, w4);
    k_srn  <<<dim3(240), dim3(256), 0, stream>>>(x);
    k_conv2<<<dim3(224), dim3(256), 0, stream>>>(g1, b1);
    k_conv3<<<dim3(96),  dim3(256), 0, stream>>>(g2, b2);
    k_conv4<<<dim3(128), dim3(256), 0, stream>>>(g3, b3);
    k_final<<<dim3(1),   dim3(256), 0, stream>>>(g4, b4, fcw, fcb, out);
}